// Round 5
// baseline (250.455 us; speedup 1.0000x reference)
//
#include <hip/hip_runtime.h>
#include <math.h>

typedef unsigned short u16;
typedef unsigned int u32;
using short8 = __attribute__((ext_vector_type(8))) short;
using f32x4  = __attribute__((ext_vector_type(4))) float;

#define SEQ 2048
#define NH 8
#define DM 512
#define DH 64
#define NROWS 4096  // B*S
#define BATCH 2
#define KVB 128

__device__ __forceinline__ float bf2f(u16 u) {
  union { u32 i; float f; } c; c.i = ((u32)u) << 16; return c.f;
}
__device__ __forceinline__ u16 f2bf(float f) {
  union { float f; u32 i; } c; c.f = f;
  u32 r = c.i + 0x7fffu + ((c.i >> 16) & 1u);
  return (u16)(r >> 16);
}

// async global->LDS, 16B per lane. LDS dest must be wave-uniform base.
__device__ __forceinline__ void gll16(const u16* g, u16* l) {
  __builtin_amdgcn_global_load_lds(
      (const __attribute__((address_space(1))) u32*)g,
      (__attribute__((address_space(3))) u32*)l, 16, 0, 0);
}

// ---------------- LayerNorm (fp32 in -> bf16 out), one wave per 512-row ----
__global__ __launch_bounds__(64) void ln_bf16_kernel(
    const float* __restrict__ x, const float* __restrict__ gw,
    const float* __restrict__ bw, u16* __restrict__ out)
{
  int row = blockIdx.x;
  int lane = threadIdx.x;
  const float* xr = x + (size_t)row * DM;
  float4 v0 = ((const float4*)xr)[lane];
  float4 v1 = ((const float4*)xr)[lane + 64];
  float s  = v0.x + v0.y + v0.z + v0.w + v1.x + v1.y + v1.z + v1.w;
  float s2 = v0.x*v0.x + v0.y*v0.y + v0.z*v0.z + v0.w*v0.w
           + v1.x*v1.x + v1.y*v1.y + v1.z*v1.z + v1.w*v1.w;
  #pragma unroll
  for (int m = 1; m < 64; m <<= 1) {
    s  += __shfl_xor(s,  m);
    s2 += __shfl_xor(s2, m);
  }
  float mu   = s * (1.0f / DM);
  float var  = s2 * (1.0f / DM) - mu * mu;
  float rstd = rsqrtf(var + 1e-5f);
  float4 ga = ((const float4*)gw)[lane],      ba = ((const float4*)bw)[lane];
  float4 gb = ((const float4*)gw)[lane + 64], bb = ((const float4*)bw)[lane + 64];
  ushort4 o0, o1;
  o0.x = f2bf((v0.x - mu) * rstd * ga.x + ba.x);
  o0.y = f2bf((v0.y - mu) * rstd * ga.y + ba.y);
  o0.z = f2bf((v0.z - mu) * rstd * ga.z + ba.z);
  o0.w = f2bf((v0.w - mu) * rstd * ga.w + ba.w);
  o1.x = f2bf((v1.x - mu) * rstd * gb.x + bb.x);
  o1.y = f2bf((v1.y - mu) * rstd * gb.y + bb.y);
  o1.z = f2bf((v1.z - mu) * rstd * gb.z + bb.z);
  o1.w = f2bf((v1.w - mu) * rstd * gb.w + bb.w);
  *(ushort4*)&out[(size_t)row * DM + lane * 4]       = o0;
  *(ushort4*)&out[(size_t)row * DM + 256 + lane * 4] = o1;
}

// ---------------- Transpose + cast fp32 (K x N) -> bf16 (N x K) ------------
__global__ __launch_bounds__(256) void transpose_cast_kernel(
    const float* __restrict__ W, u16* __restrict__ Wt, int K, int N)
{
  __shared__ float tile[32][33];
  int bn = blockIdx.x * 32, bk = blockIdx.y * 32;
  int tx = threadIdx.x & 31, ty = threadIdx.x >> 5; // 32 x 8
  #pragma unroll
  for (int i = 0; i < 32; i += 8)
    tile[ty + i][tx] = W[(size_t)(bk + ty + i) * N + bn + tx];
  __syncthreads();
  #pragma unroll
  for (int i = 0; i < 32; i += 8)
    Wt[(size_t)(bn + ty + i) * K + bk + tx] = f2bf(tile[tx][ty + i]);
}

// ---------------- Elementwise cast fp32 -> bf16 ----------------------------
__global__ __launch_bounds__(256) void cast_bf16_kernel(
    const float* __restrict__ in, u16* __restrict__ out, int n)
{
  int i = (blockIdx.x * 256 + threadIdx.x) * 4;
  if (i >= n) return;
  float4 v = *(const float4*)&in[i];
  ushort4 o;
  o.x = f2bf(v.x); o.y = f2bf(v.y); o.z = f2bf(v.z); o.w = f2bf(v.w);
  *(ushort4*)&out[i] = o;
}

// ---------------- 128xTN MFMA GEMM, BK=64, global_load_lds staging ---------
template<int TN, int MODE>
__global__ __launch_bounds__(256) void gemm_bf16(
    const u16* __restrict__ A, const u16* __restrict__ Bt,
    const float* __restrict__ bias, const float* __restrict__ res,
    float* __restrict__ outF, u16* __restrict__ outB0,
    u16* __restrict__ outB1, u16* __restrict__ outB2,
    int M, int N, int K)
{
  constexpr int NI = TN / 32;       // n-frags per wave
  __shared__ u16 sA[128 * 64];
  __shared__ u16 sB[TN * 64];
  int tid = threadIdx.x;
  int lane = tid & 63, wv = tid >> 6;
  int wm = wv >> 1, wn = wv & 1;
  int g = lane >> 4, l15 = lane & 15;
  int m0 = blockIdx.y * 128, n0 = blockIdx.x * TN;

  f32x4 acc[4][NI] = {};
  for (int k0 = 0; k0 < K; k0 += 64) {
    __syncthreads();
    #pragma unroll
    for (int s = 0; s < 4; ++s) {           // A: 128 rows x 8 chunks
      int c = s * 256 + tid;
      int row = c >> 3, p = c & 7;
      gll16(&A[(size_t)(m0 + row) * K + k0 + ((p ^ (row & 7)) * 8)],
            &sA[(size_t)(s * 256 + wv * 64) * 8]);
    }
    #pragma unroll
    for (int s = 0; s < TN / 32; ++s) {     // B: TN rows x 8 chunks
      int c = s * 256 + tid;
      int row = c >> 3, p = c & 7;
      gll16(&Bt[(size_t)(n0 + row) * K + k0 + ((p ^ (row & 7)) * 8)],
            &sB[(size_t)(s * 256 + wv * 64) * 8]);
    }
    asm volatile("s_waitcnt vmcnt(0)" ::: "memory");
    __syncthreads();
    #pragma unroll
    for (int kk = 0; kk < 2; ++kk) {
      short8 af[4], bfr[NI];
      #pragma unroll
      for (int i = 0; i < 4; ++i) {
        int row = wm * 64 + i * 16 + l15;
        af[i] = *(const short8*)&sA[row * 64 + (((4 * kk + g) ^ (row & 7)) * 8)];
      }
      #pragma unroll
      for (int i = 0; i < NI; ++i) {
        int row = wn * (TN / 2) + i * 16 + l15;
        bfr[i] = *(const short8*)&sB[row * 64 + (((4 * kk + g) ^ (row & 7)) * 8)];
      }
      #pragma unroll
      for (int mi = 0; mi < 4; ++mi)
        #pragma unroll
        for (int ni = 0; ni < NI; ++ni)
          acc[mi][ni] = __builtin_amdgcn_mfma_f32_16x16x32_bf16(af[mi], bfr[ni], acc[mi][ni], 0, 0, 0);
    }
  }

  #pragma unroll
  for (int mi = 0; mi < 4; ++mi) {
    #pragma unroll
    for (int ni = 0; ni < NI; ++ni) {
      #pragma unroll
      for (int r = 0; r < 4; ++r) {
        int grow = m0 + wm * 64 + mi * 16 + g * 4 + r;
        int gcol = n0 + wn * (TN / 2) + ni * 16 + l15;
        float val = acc[mi][ni][r] + bias[gcol];
        if (MODE == 0) {
          int part = gcol >> 9, c = gcol & 511;
          int hh = c >> 6, dd = c & 63;
          int bb = grow >> 11, ss = grow & 2047;
          size_t dst = (((size_t)(bb * NH + hh)) * SEQ + ss) * DH + dd;
          if (part == 0)      outB0[dst] = f2bf(val * 0.18033688011112042f); // q * 0.125*log2(e)
          else if (part == 1) outB1[dst] = f2bf(val);           // k
          else                outB2[dst] = f2bf(val);           // v
        } else if (MODE == 1 || MODE == 3) {
          size_t idx = (size_t)grow * DM + gcol;
          outF[idx] = val + res[idx];
        } else { // MODE 2: gelu (tanh approx = jax.nn.gelu default)
          float t = val;
          float inner = 0.7978845608028654f * (t + 0.044715f * t * t * t);
          float gl = 0.5f * t * (1.0f + tanhf(inner));
          outB0[(size_t)grow * N + gcol] = f2bf(gl);
        }
      }
    }
  }
}

// ---------------- Flash causal attention with relative positions -----------
// 1024 blocks (4/CU): block = (bh, p) handles fold pair of 16-row q-tiles
// (p, 127-p): always exactly 17 iterations of KVB=128. 4 waves = 4
// independent column-quarters with private online softmax (m sentinel -64);
// quarters merged only at the 2 flushes via LDS atomicAdd.
__global__ __launch_bounds__(256, 4) void attn_kernel(
    const u16* __restrict__ Q, const u16* __restrict__ Kb,
    const u16* __restrict__ Vb, const u16* __restrict__ Eb,
    u16* __restrict__ Ob)
{
  __shared__ u16 sK[KVB * 64];          // 16 KB, chunk-XOR layout
  __shared__ u16 sV[64 * (KVB + 8)];    // 17 KB, [d][t] block-XOR
  __shared__ u16 sP[4][16 * 32];        // 4 KB, per-wave P tiles
  __shared__ float sMLm[4][16];         // per-quarter row max
  __shared__ float sMLl[4][16];         // per-quarter row sum
  float* sO = (float*)&sP[0][0];        // 4 KB f32 overlay (flush only)

  int tid = threadIdx.x, lane = tid & 63, wc = tid >> 6;
  int g = lane >> 4, l15 = lane & 15;
  // XCD-bijective swizzle: 1024 wg / 8 XCDs -> same-head blocks colocated
  int blk = ((int)blockIdx.x & 7) * 128 + ((int)blockIdx.x >> 3);
  int bh = blk >> 6, p = blk & 63;
  int hh = bh & (NH - 1), bb = bh >> 3;

  const u16* Qh = Q  + (size_t)bh * SEQ * DH;
  const u16* Kh = Kb + (size_t)bh * SEQ * DH;
  const u16* Vh = Vb + (size_t)bh * SEQ * DH;
  const u16* Eh = Eb + (size_t)hh * SEQ * DH;

  int tileA = p, tileB = 127 - p;
  int itersA = p / 8 + 1;
  const int TOT = 17;

  int rstage = tid >> 3, cstage = (tid & 7) * 8;

  // ---- prologue: stage kt=0 ----
  #pragma unroll
  for (int s = 0; s < 4; ++s) {
    int c = s * 256 + tid, t = c >> 3, pc = c & 7;
    gll16(&Kh[(size_t)t * DH + ((pc ^ (t & 7)) * 8)],
          &sK[(size_t)(s * 256 + wc * 64) * 8]);
  }
  #pragma unroll
  for (int q = 0; q < 4; ++q) {
    int t = q * 32 + rstage;
    short8 vv = *(const short8*)&Vh[(size_t)t * DH + cstage];
    #pragma unroll
    for (int j = 0; j < 8; ++j) {
      int d = cstage + j;
      sV[d * (KVB + 8) + (((t >> 3) ^ (d >> 3)) * 8) + (t & 7)] = (u16)vv[j];
    }
  }
  asm volatile("s_waitcnt vmcnt(0)" ::: "memory");
  __syncthreads();

  short8 qf[2];
  {
    int swt = tileA * 16;
    qf[0] = *(const short8*)&Qh[(size_t)(swt + l15) * DH + g * 8];
    qf[1] = *(const short8*)&Qh[(size_t)(swt + l15) * DH + g * 8 + 32];
  }
  f32x4 o[4] = {};
  float mrow[4] = {-64.f, -64.f, -64.f, -64.f};
  float lsum[4] = {};

  auto flushOut = [&](int tile) {
    int swt = tile * 16;
    if (l15 == 0) {
      #pragma unroll
      for (int r = 0; r < 4; ++r) {
        sMLm[wc][g * 4 + r] = mrow[r];
        sMLl[wc][g * 4 + r] = lsum[r];
      }
    }
    __syncthreads();
    float scl[4];
    #pragma unroll
    for (int r = 0; r < 4; ++r) {
      int row = g * 4 + r;
      float m0 = sMLm[0][row], m1 = sMLm[1][row];
      float m2 = sMLm[2][row], m3 = sMLm[3][row];
      float mt = fmaxf(fmaxf(m0, m1), fmaxf(m2, m3));
      float lt = sMLl[0][row] * exp2f(m0 - mt) + sMLl[1][row] * exp2f(m1 - mt)
               + sMLl[2][row] * exp2f(m2 - mt) + sMLl[3][row] * exp2f(m3 - mt);
      scl[r] = exp2f(mrow[r] - mt) / lt;
    }
    if (wc == 0) {
      #pragma unroll
      for (int r = 0; r < 4; ++r)
        #pragma unroll
        for (int nb = 0; nb < 4; ++nb)
          sO[(g * 4 + r) * 64 + nb * 16 + l15] = o[nb][r] * scl[r];
    }
    __syncthreads();
    if (wc != 0) {
      #pragma unroll
      for (int r = 0; r < 4; ++r)
        #pragma unroll
        for (int nb = 0; nb < 4; ++nb)
          atomicAdd(&sO[(g * 4 + r) * 64 + nb * 16 + l15], o[nb][r] * scl[r]);
    }
    __syncthreads();
    #pragma unroll
    for (int rr = 0; rr < 4; ++rr) {
      int row = wc * 4 + rr;
      float val = sO[row * 64 + lane];
      Ob[((size_t)(bb * SEQ + swt + row)) * DM + hh * DH + lane] = f2bf(val);
    }
    __syncthreads();
  };

  for (int it = 0; it < TOT; ++it) {
    if (it == itersA) {
      flushOut(tileA);
      #pragma unroll
      for (int nb = 0; nb < 4; ++nb) o[nb] = f32x4{};
      #pragma unroll
      for (int r = 0; r < 4; ++r) { mrow[r] = -64.f; lsum[r] = 0.f; }
      int swt = tileB * 16;
      qf[0] = *(const short8*)&Qh[(size_t)(swt + l15) * DH + g * 8];
      qf[1] = *(const short8*)&Qh[(size_t)(swt + l15) * DH + g * 8 + 32];
    }
    int tile = (it < itersA) ? tileA : tileB;
    int kt   = (it < itersA) ? it : it - itersA;
    int swt = tile * 16, t0 = kt * KVB;

    // prefetch next K,V into regs (issue early, write after B1)
    bool pre = (it + 1 < TOT);
    short8 kp[4], vp[4];
    if (pre) {
      int kn = (it + 1 < itersA) ? it + 1 : it + 1 - itersA;
      int tb = kn * KVB;
      #pragma unroll
      for (int s = 0; s < 4; ++s)
        kp[s] = *(const short8*)&Kh[(size_t)(tb + s * 32 + rstage) * DH + cstage];
      #pragma unroll
      for (int s = 0; s < 4; ++s)
        vp[s] = *(const short8*)&Vh[(size_t)(tb + s * 32 + rstage) * DH + cstage];
    }

    // S1 = Q K^T (16 rows x 32 cols: this wave's quarter)
    f32x4 accS[2];
    #pragma unroll
    for (int ni = 0; ni < 2; ++ni) {
      int row = wc * 32 + ni * 16 + l15;
      short8 k0 = *(const short8*)&sK[row * 64 + ((g ^ (row & 7)) * 8)];
      short8 k1 = *(const short8*)&sK[row * 64 + (((4 + g) ^ (row & 7)) * 8)];
      f32x4 z = {};
      z = __builtin_amdgcn_mfma_f32_16x16x32_bf16(qf[0], k0, z, 0, 0, 0);
      z = __builtin_amdgcn_mfma_f32_16x16x32_bf16(qf[1], k1, z, 0, 0, 0);
      accS[ni] = z;
    }

    // S2 = Q E^T strip (16 x 48): rel[s,t] = q[s].E[2047 - s + t]
    int jbase = 2032 - swt + t0 + wc * 32;
    f32x4 accR[3];
    #pragma unroll
    for (int nb = 0; nb < 3; ++nb) {
      int j = jbase + nb * 16 + l15; if (j > 2047) j = 2047;
      short8 e0 = *(const short8*)&Eh[(size_t)j * DH + g * 8];
      short8 e1 = *(const short8*)&Eh[(size_t)j * DH + 32 + g * 8];
      f32x4 z = {};
      z = __builtin_amdgcn_mfma_f32_16x16x32_bf16(qf[0], e0, z, 0, 0, 0);
      z = __builtin_amdgcn_mfma_f32_16x16x32_bf16(qf[1], e1, z, 0, 0, 0);
      accR[nb] = z;
    }

    // skew realign + combine + causal mask
    bool needMask = (t0 + wc * 32 + 31 > swt);
    #pragma unroll
    for (int r = 0; r < 4; ++r) {
      int srow = g * 4 + r;
      int dsh = 15 - srow + l15;                 // 0..30
      int srcl = (lane & 48) + (dsh & 15);
      float sh0 = __shfl(accR[0][r], srcl);
      float sh1 = __shfl(accR[1][r], srcl);
      float sh2 = __shfl(accR[2][r], srcl);
      bool cy = dsh >= 16;
      float rel0 = cy ? sh1 : sh0;
      float rel1 = cy ? sh2 : sh1;
      float v0 = accS[0][r] + rel0;
      float v1 = accS[1][r] + rel1;
      if (needMask) {
        if (t0 + wc * 32 + l15 > swt + srow)      v0 = -1e30f;
        if (t0 + wc * 32 + 16 + l15 > swt + srow) v1 = -1e30f;
      }
      accS[0][r] = v0; accS[1][r] = v1;
    }

    // private online softmax (quarter-local max; sentinel -64)
    #pragma unroll
    for (int r = 0; r < 4; ++r) {
      float tm = fmaxf(accS[0][r], accS[1][r]);
      tm = fmaxf(tm, __shfl_xor(tm, 1));
      tm = fmaxf(tm, __shfl_xor(tm, 2));
      tm = fmaxf(tm, __shfl_xor(tm, 4));
      tm = fmaxf(tm, __shfl_xor(tm, 8));
      float mnew = fmaxf(mrow[r], tm);
      float scl = exp2f(mrow[r] - mnew);
      mrow[r] = mnew;
      float p0 = exp2f(accS[0][r] - mnew);
      float p1 = exp2f(accS[1][r] - mnew);
      accS[0][r] = p0; accS[1][r] = p1;
      float se = p0 + p1;
      se += __shfl_xor(se, 1); se += __shfl_xor(se, 2);
      se += __shfl_xor(se, 4); se += __shfl_xor(se, 8);
      lsum[r] = lsum[r] * scl + se;
      o[0][r] *= scl; o[1][r] *= scl; o[2][r] *= scl; o[3][r] *= scl;
    }

    // P -> per-wave LDS (chunk-XOR by row&3), then PV
    #pragma unroll
    for (int ni = 0; ni < 2; ++ni)
      #pragma unroll
      for (int r = 0; r < 4; ++r) {
        int srow = g * 4 + r;
        int chunk = (ni * 2 + (l15 >> 3)) ^ (srow & 3);
        sP[wc][srow * 32 + chunk * 8 + (l15 & 7)] = f2bf(accS[ni][r]);
      }
    asm volatile("s_waitcnt lgkmcnt(0)" ::: "memory");
    __builtin_amdgcn_sched_barrier(0);
    {
      short8 pf = *(const short8*)&sP[wc][l15 * 32 + ((g ^ (l15 & 3)) * 8)];
      #pragma unroll
      for (int nb = 0; nb < 4; ++nb) {
        int d = nb * 16 + l15;
        int ck = wc * 4 + g;
        short8 vf = *(const short8*)&sV[d * (KVB + 8) + ((ck ^ (d >> 3)) * 8)];
        o[nb] = __builtin_amdgcn_mfma_f32_16x16x32_bf16(pf, vf, o[nb], 0, 0, 0);
      }
    }

    __syncthreads();                              // B1: LDS reads done
    if (pre) {
      #pragma unroll
      for (int s = 0; s < 4; ++s) {
        int row = s * 32 + rstage;
        *(short8*)&sK[row * 64 + (((tid & 7) ^ (row & 7)) * 8)] = kp[s];
      }
      #pragma unroll
      for (int s = 0; s < 4; ++s) {
        int t = s * 32 + rstage;
        #pragma unroll
        for (int j = 0; j < 8; ++j) {
          int d = cstage + j;
          sV[d * (KVB + 8) + (((t >> 3) ^ (d >> 3)) * 8) + (t & 7)] = (u16)vp[s][j];
        }
      }
    }
    __syncthreads();                              // B2: writes visible
  }

  flushOut(tileB);
}

// ---------------------------------------------------------------------------
extern "C" void kernel_launch(void* const* d_in, const int* in_sizes, int n_in,
                              void* d_out, int out_size, void* d_ws, size_t ws_size,
                              hipStream_t stream) {
  const float* x     = (const float*)d_in[0];
  // d_in[1] = mask: recomputed causally in-kernel
  const float* Wqkv  = (const float*)d_in[2];
  const float* bqkv  = (const float*)d_in[3];
  const float* Wproj = (const float*)d_in[4];
  const float* bproj = (const float*)d_in[5];
  const float* E     = (const float*)d_in[6];
  const float* g1    = (const float*)d_in[7];
  const float* b1    = (const float*)d_in[8];
  const float* g2    = (const float*)d_in[9];
  const float* b2    = (const float*)d_in[10];
  const float* W1    = (const float*)d_in[11];
  const float* bm1   = (const float*)d_in[12];
  const float* W2    = (const float*)d_in[13];
  const float* bm2   = (const float*)d_in[14];
  float* out = (float*)d_out;

  char* ws = (char*)d_ws;
  size_t off = 0;
  auto alloc = [&](size_t bytes) {
    void* p = ws + off;
    off += (bytes + 255) & ~(size_t)255;
    return p;
  };
  u16* a_bf   = (u16*)alloc((size_t)NROWS * DM * 2);      // LN1 out, reused for LN2 out
  u16* q_bf   = (u16*)alloc((size_t)NROWS * DM * 2);
  u16* k_bf   = (u16*)alloc((size_t)NROWS * DM * 2);
  u16* v_bf   = (u16*)alloc((size_t)NROWS * DM * 2);
  u16* att_bf = (u16*)alloc((size_t)NROWS * DM * 2);
  float* y    = (float*)alloc((size_t)NROWS * DM * 4);
  u16* h_bf   = (u16*)alloc((size_t)NROWS * 2048 * 2);
  u16* WqkvT  = (u16*)alloc((size_t)1536 * 512 * 2);
  u16* WprojT = (u16*)alloc((size_t)512 * 512 * 2);
  u16* W1T    = (u16*)alloc((size_t)2048 * 512 * 2);
  u16* W2T    = (u16*)alloc((size_t)512 * 2048 * 2);
  u16* E_bf   = (u16*)alloc((size_t)NH * SEQ * DH * 2);

  // weights -> bf16 (transposed to N x K)
  transpose_cast_kernel<<<dim3(1536 / 32, 512 / 32), 256, 0, stream>>>(Wqkv, WqkvT, 512, 1536);
  transpose_cast_kernel<<<dim3(512 / 32, 512 / 32), 256, 0, stream>>>(Wproj, WprojT, 512, 512);
  transpose_cast_kernel<<<dim3(2048 / 32, 512 / 32), 256, 0, stream>>>(W1, W1T, 512, 2048);
  transpose_cast_kernel<<<dim3(512 / 32, 2048 / 32), 256, 0, stream>>>(W2, W2T, 2048, 512);
  cast_bf16_kernel<<<(NH * SEQ * DH) / (256 * 4), 256, 0, stream>>>(E, E_bf, NH * SEQ * DH);

  // LN1
  ln_bf16_kernel<<<NROWS, 64, 0, stream>>>(x, g1, b1, a_bf);
  // QKV (q pre-scaled by 0.125*log2e for exp2-softmax)
  gemm_bf16<128, 0><<<dim3(1536 / 128, NROWS / 128), 256, 0, stream>>>(
      a_bf, WqkvT, bqkv, nullptr, nullptr, q_bf, k_bf, v_bf, NROWS, 1536, 512);
  // attention (1024 blocks, 4/CU, quarter-split waves)
  attn_kernel<<<1024, 256, 0, stream>>>(q_bf, k_bf, v_bf, E_bf, att_bf);
  // proj + residual -> y (fp32)
  gemm_bf16<64, 1><<<dim3(512 / 64, NROWS / 128), 256, 0, stream>>>(
      att_bf, WprojT, bproj, x, y, nullptr, nullptr, nullptr, NROWS, 512, 512);
  // LN2 (reuse a_bf as m_bf)
  ln_bf16_kernel<<<NROWS, 64, 0, stream>>>(y, g2, b2, a_bf);
  // FFN1 + gelu
  gemm_bf16<128, 2><<<dim3(2048 / 128, NROWS / 128), 256, 0, stream>>>(
      a_bf, W1T, bm1, nullptr, nullptr, h_bf, nullptr, nullptr, NROWS, 2048, 512);
  // FFN2 + residual -> out
  gemm_bf16<64, 3><<<dim3(512 / 64, NROWS / 128), 256, 0, stream>>>(
      h_bf, W2T, bm2, y, out, nullptr, nullptr, nullptr, NROWS, 512, 2048);
}

// Round 6
// 241.637 us; speedup vs baseline: 1.0365x; 1.0365x over previous
//
#include <hip/hip_runtime.h>
#include <math.h>

typedef unsigned short u16;
typedef unsigned int u32;
using short8 = __attribute__((ext_vector_type(8))) short;
using f32x4  = __attribute__((ext_vector_type(4))) float;

#define SEQ 2048
#define NH 8
#define DM 512
#define DH 64
#define NROWS 4096  // B*S
#define BATCH 2
#define KVB 128

__device__ __forceinline__ float bf2f(u16 u) {
  union { u32 i; float f; } c; c.i = ((u32)u) << 16; return c.f;
}
__device__ __forceinline__ u16 f2bf(float f) {
  union { float f; u32 i; } c; c.f = f;
  u32 r = c.i + 0x7fffu + ((c.i >> 16) & 1u);
  return (u16)(r >> 16);
}

// async global->LDS, 16B per lane. LDS dest must be wave-uniform base.
__device__ __forceinline__ void gll16(const u16* g, u16* l) {
  __builtin_amdgcn_global_load_lds(
      (const __attribute__((address_space(1))) u32*)g,
      (__attribute__((address_space(3))) u32*)l, 16, 0, 0);
}

// ---------------- LayerNorm (fp32 in -> bf16 out), one wave per 512-row ----
__global__ __launch_bounds__(64) void ln_bf16_kernel(
    const float* __restrict__ x, const float* __restrict__ gw,
    const float* __restrict__ bw, u16* __restrict__ out)
{
  int row = blockIdx.x;
  int lane = threadIdx.x;
  const float* xr = x + (size_t)row * DM;
  float4 v0 = ((const float4*)xr)[lane];
  float4 v1 = ((const float4*)xr)[lane + 64];
  float s  = v0.x + v0.y + v0.z + v0.w + v1.x + v1.y + v1.z + v1.w;
  float s2 = v0.x*v0.x + v0.y*v0.y + v0.z*v0.z + v0.w*v0.w
           + v1.x*v1.x + v1.y*v1.y + v1.z*v1.z + v1.w*v1.w;
  #pragma unroll
  for (int m = 1; m < 64; m <<= 1) {
    s  += __shfl_xor(s,  m);
    s2 += __shfl_xor(s2, m);
  }
  float mu   = s * (1.0f / DM);
  float var  = s2 * (1.0f / DM) - mu * mu;
  float rstd = rsqrtf(var + 1e-5f);
  float4 ga = ((const float4*)gw)[lane],      ba = ((const float4*)bw)[lane];
  float4 gb = ((const float4*)gw)[lane + 64], bb = ((const float4*)bw)[lane + 64];
  ushort4 o0, o1;
  o0.x = f2bf((v0.x - mu) * rstd * ga.x + ba.x);
  o0.y = f2bf((v0.y - mu) * rstd * ga.y + ba.y);
  o0.z = f2bf((v0.z - mu) * rstd * ga.z + ba.z);
  o0.w = f2bf((v0.w - mu) * rstd * ga.w + ba.w);
  o1.x = f2bf((v1.x - mu) * rstd * gb.x + bb.x);
  o1.y = f2bf((v1.y - mu) * rstd * gb.y + bb.y);
  o1.z = f2bf((v1.z - mu) * rstd * gb.z + bb.z);
  o1.w = f2bf((v1.w - mu) * rstd * gb.w + bb.w);
  *(ushort4*)&out[(size_t)row * DM + lane * 4]       = o0;
  *(ushort4*)&out[(size_t)row * DM + 256 + lane * 4] = o1;
}

// ---------------- Transpose + cast fp32 (K x N) -> bf16 (N x K) ------------
__global__ __launch_bounds__(256) void transpose_cast_kernel(
    const float* __restrict__ W, u16* __restrict__ Wt, int K, int N)
{
  __shared__ float tile[32][33];
  int bn = blockIdx.x * 32, bk = blockIdx.y * 32;
  int tx = threadIdx.x & 31, ty = threadIdx.x >> 5; // 32 x 8
  #pragma unroll
  for (int i = 0; i < 32; i += 8)
    tile[ty + i][tx] = W[(size_t)(bk + ty + i) * N + bn + tx];
  __syncthreads();
  #pragma unroll
  for (int i = 0; i < 32; i += 8)
    Wt[(size_t)(bn + ty + i) * K + bk + tx] = f2bf(tile[tx][ty + i]);
}

// ---------------- Elementwise cast fp32 -> bf16 ----------------------------
__global__ __launch_bounds__(256) void cast_bf16_kernel(
    const float* __restrict__ in, u16* __restrict__ out, int n)
{
  int i = (blockIdx.x * 256 + threadIdx.x) * 4;
  if (i >= n) return;
  float4 v = *(const float4*)&in[i];
  ushort4 o;
  o.x = f2bf(v.x); o.y = f2bf(v.y); o.z = f2bf(v.z); o.w = f2bf(v.w);
  *(ushort4*)&out[i] = o;
}

// ---------------- 128xTN MFMA GEMM, BK=64, global_load_lds staging ---------
template<int TN, int MODE>
__global__ __launch_bounds__(256) void gemm_bf16(
    const u16* __restrict__ A, const u16* __restrict__ Bt,
    const float* __restrict__ bias, const float* __restrict__ res,
    float* __restrict__ outF, u16* __restrict__ outB0,
    u16* __restrict__ outB1, u16* __restrict__ outB2,
    int M, int N, int K)
{
  constexpr int NI = TN / 32;       // n-frags per wave
  __shared__ u16 sA[128 * 64];
  __shared__ u16 sB[TN * 64];
  int tid = threadIdx.x;
  int lane = tid & 63, wv = tid >> 6;
  int wm = wv >> 1, wn = wv & 1;
  int g = lane >> 4, l15 = lane & 15;
  int m0 = blockIdx.y * 128, n0 = blockIdx.x * TN;

  f32x4 acc[4][NI] = {};
  for (int k0 = 0; k0 < K; k0 += 64) {
    __syncthreads();
    #pragma unroll
    for (int s = 0; s < 4; ++s) {           // A: 128 rows x 8 chunks
      int c = s * 256 + tid;
      int row = c >> 3, p = c & 7;
      gll16(&A[(size_t)(m0 + row) * K + k0 + ((p ^ (row & 7)) * 8)],
            &sA[(size_t)(s * 256 + wv * 64) * 8]);
    }
    #pragma unroll
    for (int s = 0; s < TN / 32; ++s) {     // B: TN rows x 8 chunks
      int c = s * 256 + tid;
      int row = c >> 3, p = c & 7;
      gll16(&Bt[(size_t)(n0 + row) * K + k0 + ((p ^ (row & 7)) * 8)],
            &sB[(size_t)(s * 256 + wv * 64) * 8]);
    }
    asm volatile("s_waitcnt vmcnt(0)" ::: "memory");
    __syncthreads();
    #pragma unroll
    for (int kk = 0; kk < 2; ++kk) {
      short8 af[4], bfr[NI];
      #pragma unroll
      for (int i = 0; i < 4; ++i) {
        int row = wm * 64 + i * 16 + l15;
        af[i] = *(const short8*)&sA[row * 64 + (((4 * kk + g) ^ (row & 7)) * 8)];
      }
      #pragma unroll
      for (int i = 0; i < NI; ++i) {
        int row = wn * (TN / 2) + i * 16 + l15;
        bfr[i] = *(const short8*)&sB[row * 64 + (((4 * kk + g) ^ (row & 7)) * 8)];
      }
      #pragma unroll
      for (int mi = 0; mi < 4; ++mi)
        #pragma unroll
        for (int ni = 0; ni < NI; ++ni)
          acc[mi][ni] = __builtin_amdgcn_mfma_f32_16x16x32_bf16(af[mi], bfr[ni], acc[mi][ni], 0, 0, 0);
    }
  }

  #pragma unroll
  for (int mi = 0; mi < 4; ++mi) {
    #pragma unroll
    for (int ni = 0; ni < NI; ++ni) {
      #pragma unroll
      for (int r = 0; r < 4; ++r) {
        int grow = m0 + wm * 64 + mi * 16 + g * 4 + r;
        int gcol = n0 + wn * (TN / 2) + ni * 16 + l15;
        float val = acc[mi][ni][r] + bias[gcol];
        if (MODE == 0) {
          int part = gcol >> 9, c = gcol & 511;
          int hh = c >> 6, dd = c & 63;
          int bb = grow >> 11, ss = grow & 2047;
          size_t dst = (((size_t)(bb * NH + hh)) * SEQ + ss) * DH + dd;
          if (part == 0)      outB0[dst] = f2bf(val * 0.18033688011112042f); // q * 0.125*log2(e)
          else if (part == 1) outB1[dst] = f2bf(val);           // k
          else                outB2[dst] = f2bf(val);           // v
        } else if (MODE == 1 || MODE == 3) {
          size_t idx = (size_t)grow * DM + gcol;
          outF[idx] = val + res[idx];
        } else { // MODE 2: gelu (tanh approx = jax.nn.gelu default)
          float t = val;
          float inner = 0.7978845608028654f * (t + 0.044715f * t * t * t);
          float gl = 0.5f * t * (1.0f + tanhf(inner));
          outB0[(size_t)grow * N + gcol] = f2bf(gl);
        }
      }
    }
  }
}

// ---------------- Flash causal attention with relative positions -----------
// 1024 blocks: block = (bh, p) handles fold pair of 16-row q-tiles
// (p, 127-p): always exactly 17 iterations of KVB=128. 4 waves = 4
// independent column-quarters with private online softmax (m sentinel -64);
// quarters merged only at the 2 flushes. launch_bounds(256,3): VGPR cap
// ~170 so the ~110-reg body does NOT spill (R5's (256,4) forced 64 VGPR
// -> 35MB scratch writes).
__global__ __launch_bounds__(256, 3) void attn_kernel(
    const u16* __restrict__ Q, const u16* __restrict__ Kb,
    const u16* __restrict__ Vb, const u16* __restrict__ Eb,
    u16* __restrict__ Ob)
{
  __shared__ u16 sK[KVB * 64];          // 16 KB, chunk-XOR layout
  __shared__ u16 sV[64 * (KVB + 8)];    // 17 KB, [d][t] block-XOR
  __shared__ u16 sP[4][16 * 32];        // 4 KB, per-wave P tiles
  __shared__ float sMLm[4][16];         // per-quarter row max
  __shared__ float sMLl[4][16];         // per-quarter row sum
  float* sO = (float*)&sP[0][0];        // 4 KB f32 overlay (flush only)

  int tid = threadIdx.x, lane = tid & 63, wc = tid >> 6;
  int g = lane >> 4, l15 = lane & 15;
  // XCD-bijective swizzle: 1024 wg / 8 XCDs -> same-head blocks colocated
  int blk = ((int)blockIdx.x & 7) * 128 + ((int)blockIdx.x >> 3);
  int bh = blk >> 6, p = blk & 63;
  int hh = bh & (NH - 1), bb = bh >> 3;

  const u16* Qh = Q  + (size_t)bh * SEQ * DH;
  const u16* Kh = Kb + (size_t)bh * SEQ * DH;
  const u16* Vh = Vb + (size_t)bh * SEQ * DH;
  const u16* Eh = Eb + (size_t)hh * SEQ * DH;

  int tileA = p, tileB = 127 - p;
  int itersA = p / 8 + 1;
  const int TOT = 17;

  int rstage = tid >> 3, cstage = (tid & 7) * 8;

  // ---- prologue: stage kt=0 ----
  #pragma unroll
  for (int s = 0; s < 4; ++s) {
    int c = s * 256 + tid, t = c >> 3, pc = c & 7;
    gll16(&Kh[(size_t)t * DH + ((pc ^ (t & 7)) * 8)],
          &sK[(size_t)(s * 256 + wc * 64) * 8]);
  }
  #pragma unroll
  for (int q = 0; q < 4; ++q) {
    int t = q * 32 + rstage;
    short8 vv = *(const short8*)&Vh[(size_t)t * DH + cstage];
    #pragma unroll
    for (int j = 0; j < 8; ++j) {
      int d = cstage + j;
      sV[d * (KVB + 8) + (((t >> 3) ^ (d >> 3)) * 8) + (t & 7)] = (u16)vv[j];
    }
  }
  asm volatile("s_waitcnt vmcnt(0)" ::: "memory");
  __syncthreads();

  short8 qf[2];
  {
    int swt = tileA * 16;
    qf[0] = *(const short8*)&Qh[(size_t)(swt + l15) * DH + g * 8];
    qf[1] = *(const short8*)&Qh[(size_t)(swt + l15) * DH + g * 8 + 32];
  }
  f32x4 o[4] = {};
  float mrow[4] = {-64.f, -64.f, -64.f, -64.f};
  float lsum[4] = {};

  auto flushOut = [&](int tile) {
    int swt = tile * 16;
    if (l15 == 0) {
      #pragma unroll
      for (int r = 0; r < 4; ++r) {
        sMLm[wc][g * 4 + r] = mrow[r];
        sMLl[wc][g * 4 + r] = lsum[r];
      }
    }
    __syncthreads();
    float scl[4];
    #pragma unroll
    for (int r = 0; r < 4; ++r) {
      int row = g * 4 + r;
      float m0 = sMLm[0][row], m1 = sMLm[1][row];
      float m2 = sMLm[2][row], m3 = sMLm[3][row];
      float mt = fmaxf(fmaxf(m0, m1), fmaxf(m2, m3));
      float lt = sMLl[0][row] * exp2f(m0 - mt) + sMLl[1][row] * exp2f(m1 - mt)
               + sMLl[2][row] * exp2f(m2 - mt) + sMLl[3][row] * exp2f(m3 - mt);
      scl[r] = exp2f(mrow[r] - mt) / lt;
    }
    if (wc == 0) {
      #pragma unroll
      for (int r = 0; r < 4; ++r)
        #pragma unroll
        for (int nb = 0; nb < 4; ++nb)
          sO[(g * 4 + r) * 64 + nb * 16 + l15] = o[nb][r] * scl[r];
    }
    __syncthreads();
    if (wc != 0) {
      #pragma unroll
      for (int r = 0; r < 4; ++r)
        #pragma unroll
        for (int nb = 0; nb < 4; ++nb)
          atomicAdd(&sO[(g * 4 + r) * 64 + nb * 16 + l15], o[nb][r] * scl[r]);
    }
    __syncthreads();
    #pragma unroll
    for (int rr = 0; rr < 4; ++rr) {
      int row = wc * 4 + rr;
      float val = sO[row * 64 + lane];
      Ob[((size_t)(bb * SEQ + swt + row)) * DM + hh * DH + lane] = f2bf(val);
    }
    __syncthreads();
  };

  for (int it = 0; it < TOT; ++it) {
    if (it == itersA) {
      flushOut(tileA);
      #pragma unroll
      for (int nb = 0; nb < 4; ++nb) o[nb] = f32x4{};
      #pragma unroll
      for (int r = 0; r < 4; ++r) { mrow[r] = -64.f; lsum[r] = 0.f; }
      int swt = tileB * 16;
      qf[0] = *(const short8*)&Qh[(size_t)(swt + l15) * DH + g * 8];
      qf[1] = *(const short8*)&Qh[(size_t)(swt + l15) * DH + g * 8 + 32];
    }
    int tile = (it < itersA) ? tileA : tileB;
    int kt   = (it < itersA) ? it : it - itersA;
    int swt = tile * 16, t0 = kt * KVB;

    // prefetch next K,V into regs (issue early, write after B1)
    bool pre = (it + 1 < TOT);
    short8 kp[4], vp[4];
    if (pre) {
      int kn = (it + 1 < itersA) ? it + 1 : it + 1 - itersA;
      int tb = kn * KVB;
      #pragma unroll
      for (int s = 0; s < 4; ++s)
        kp[s] = *(const short8*)&Kh[(size_t)(tb + s * 32 + rstage) * DH + cstage];
      #pragma unroll
      for (int s = 0; s < 4; ++s)
        vp[s] = *(const short8*)&Vh[(size_t)(tb + s * 32 + rstage) * DH + cstage];
    }

    // S1 = Q K^T (16 rows x 32 cols: this wave's quarter)
    f32x4 accS[2];
    #pragma unroll
    for (int ni = 0; ni < 2; ++ni) {
      int row = wc * 32 + ni * 16 + l15;
      short8 k0 = *(const short8*)&sK[row * 64 + ((g ^ (row & 7)) * 8)];
      short8 k1 = *(const short8*)&sK[row * 64 + (((4 + g) ^ (row & 7)) * 8)];
      f32x4 z = {};
      z = __builtin_amdgcn_mfma_f32_16x16x32_bf16(qf[0], k0, z, 0, 0, 0);
      z = __builtin_amdgcn_mfma_f32_16x16x32_bf16(qf[1], k1, z, 0, 0, 0);
      accS[ni] = z;
    }

    // S2 = Q E^T strip (16 x 48): rel[s,t] = q[s].E[2047 - s + t]
    int jbase = 2032 - swt + t0 + wc * 32;
    f32x4 accR[3];
    #pragma unroll
    for (int nb = 0; nb < 3; ++nb) {
      int j = jbase + nb * 16 + l15; if (j > 2047) j = 2047;
      short8 e0 = *(const short8*)&Eh[(size_t)j * DH + g * 8];
      short8 e1 = *(const short8*)&Eh[(size_t)j * DH + 32 + g * 8];
      f32x4 z = {};
      z = __builtin_amdgcn_mfma_f32_16x16x32_bf16(qf[0], e0, z, 0, 0, 0);
      z = __builtin_amdgcn_mfma_f32_16x16x32_bf16(qf[1], e1, z, 0, 0, 0);
      accR[nb] = z;
    }

    // skew realign + combine + causal mask
    bool needMask = (t0 + wc * 32 + 31 > swt);
    #pragma unroll
    for (int r = 0; r < 4; ++r) {
      int srow = g * 4 + r;
      int dsh = 15 - srow + l15;                 // 0..30
      int srcl = (lane & 48) + (dsh & 15);
      float sh0 = __shfl(accR[0][r], srcl);
      float sh1 = __shfl(accR[1][r], srcl);
      float sh2 = __shfl(accR[2][r], srcl);
      bool cy = dsh >= 16;
      float rel0 = cy ? sh1 : sh0;
      float rel1 = cy ? sh2 : sh1;
      float v0 = accS[0][r] + rel0;
      float v1 = accS[1][r] + rel1;
      if (needMask) {
        if (t0 + wc * 32 + l15 > swt + srow)      v0 = -1e30f;
        if (t0 + wc * 32 + 16 + l15 > swt + srow) v1 = -1e30f;
      }
      accS[0][r] = v0; accS[1][r] = v1;
    }

    // private online softmax (quarter-local max; sentinel -64)
    #pragma unroll
    for (int r = 0; r < 4; ++r) {
      float tm = fmaxf(accS[0][r], accS[1][r]);
      tm = fmaxf(tm, __shfl_xor(tm, 1));
      tm = fmaxf(tm, __shfl_xor(tm, 2));
      tm = fmaxf(tm, __shfl_xor(tm, 4));
      tm = fmaxf(tm, __shfl_xor(tm, 8));
      float mnew = fmaxf(mrow[r], tm);
      float scl = exp2f(mrow[r] - mnew);
      mrow[r] = mnew;
      float p0 = exp2f(accS[0][r] - mnew);
      float p1 = exp2f(accS[1][r] - mnew);
      accS[0][r] = p0; accS[1][r] = p1;
      float se = p0 + p1;
      se += __shfl_xor(se, 1); se += __shfl_xor(se, 2);
      se += __shfl_xor(se, 4); se += __shfl_xor(se, 8);
      lsum[r] = lsum[r] * scl + se;
      o[0][r] *= scl; o[1][r] *= scl; o[2][r] *= scl; o[3][r] *= scl;
    }

    // P -> per-wave LDS (chunk-XOR by row&3), then PV
    #pragma unroll
    for (int ni = 0; ni < 2; ++ni)
      #pragma unroll
      for (int r = 0; r < 4; ++r) {
        int srow = g * 4 + r;
        int chunk = (ni * 2 + (l15 >> 3)) ^ (srow & 3);
        sP[wc][srow * 32 + chunk * 8 + (l15 & 7)] = f2bf(accS[ni][r]);
      }
    asm volatile("s_waitcnt lgkmcnt(0)" ::: "memory");
    __builtin_amdgcn_sched_barrier(0);
    {
      short8 pf = *(const short8*)&sP[wc][l15 * 32 + ((g ^ (l15 & 3)) * 8)];
      #pragma unroll
      for (int nb = 0; nb < 4; ++nb) {
        int d = nb * 16 + l15;
        int ck = wc * 4 + g;
        short8 vf = *(const short8*)&sV[d * (KVB + 8) + ((ck ^ (d >> 3)) * 8)];
        o[nb] = __builtin_amdgcn_mfma_f32_16x16x32_bf16(pf, vf, o[nb], 0, 0, 0);
      }
    }

    __syncthreads();                              // B1: LDS reads done
    if (pre) {
      #pragma unroll
      for (int s = 0; s < 4; ++s) {
        int row = s * 32 + rstage;
        *(short8*)&sK[row * 64 + (((tid & 7) ^ (row & 7)) * 8)] = kp[s];
      }
      #pragma unroll
      for (int s = 0; s < 4; ++s) {
        int t = s * 32 + rstage;
        #pragma unroll
        for (int j = 0; j < 8; ++j) {
          int d = cstage + j;
          sV[d * (KVB + 8) + (((t >> 3) ^ (d >> 3)) * 8) + (t & 7)] = (u16)vp[s][j];
        }
      }
    }
    __syncthreads();                              // B2: writes visible
  }

  flushOut(tileB);
}

// ---------------------------------------------------------------------------
extern "C" void kernel_launch(void* const* d_in, const int* in_sizes, int n_in,
                              void* d_out, int out_size, void* d_ws, size_t ws_size,
                              hipStream_t stream) {
  const float* x     = (const float*)d_in[0];
  // d_in[1] = mask: recomputed causally in-kernel
  const float* Wqkv  = (const float*)d_in[2];
  const float* bqkv  = (const float*)d_in[3];
  const float* Wproj = (const float*)d_in[4];
  const float* bproj = (const float*)d_in[5];
  const float* E     = (const float*)d_in[6];
  const float* g1    = (const float*)d_in[7];
  const float* b1    = (const float*)d_in[8];
  const float* g2    = (const float*)d_in[9];
  const float* b2    = (const float*)d_in[10];
  const float* W1    = (const float*)d_in[11];
  const float* bm1   = (const float*)d_in[12];
  const float* W2    = (const float*)d_in[13];
  const float* bm2   = (const float*)d_in[14];
  float* out = (float*)d_out;

  char* ws = (char*)d_ws;
  size_t off = 0;
  auto alloc = [&](size_t bytes) {
    void* p = ws + off;
    off += (bytes + 255) & ~(size_t)255;
    return p;
  };
  u16* a_bf   = (u16*)alloc((size_t)NROWS * DM * 2);      // LN1 out, reused for LN2 out
  u16* q_bf   = (u16*)alloc((size_t)NROWS * DM * 2);
  u16* k_bf   = (u16*)alloc((size_t)NROWS * DM * 2);
  u16* v_bf   = (u16*)alloc((size_t)NROWS * DM * 2);
  u16* att_bf = (u16*)alloc((size_t)NROWS * DM * 2);
  float* y    = (float*)alloc((size_t)NROWS * DM * 4);
  u16* h_bf   = (u16*)alloc((size_t)NROWS * 2048 * 2);
  u16* WqkvT  = (u16*)alloc((size_t)1536 * 512 * 2);
  u16* WprojT = (u16*)alloc((size_t)512 * 512 * 2);
  u16* W1T    = (u16*)alloc((size_t)2048 * 512 * 2);
  u16* W2T    = (u16*)alloc((size_t)512 * 2048 * 2);
  u16* E_bf   = (u16*)alloc((size_t)NH * SEQ * DH * 2);

  // weights -> bf16 (transposed to N x K)
  transpose_cast_kernel<<<dim3(1536 / 32, 512 / 32), 256, 0, stream>>>(Wqkv, WqkvT, 512, 1536);
  transpose_cast_kernel<<<dim3(512 / 32, 512 / 32), 256, 0, stream>>>(Wproj, WprojT, 512, 512);
  transpose_cast_kernel<<<dim3(2048 / 32, 512 / 32), 256, 0, stream>>>(W1, W1T, 512, 2048);
  transpose_cast_kernel<<<dim3(512 / 32, 2048 / 32), 256, 0, stream>>>(W2, W2T, 2048, 512);
  cast_bf16_kernel<<<(NH * SEQ * DH) / (256 * 4), 256, 0, stream>>>(E, E_bf, NH * SEQ * DH);

  // LN1
  ln_bf16_kernel<<<NROWS, 64, 0, stream>>>(x, g1, b1, a_bf);
  // QKV (q pre-scaled by 0.125*log2e for exp2-softmax)
  gemm_bf16<128, 0><<<dim3(1536 / 128, NROWS / 128), 256, 0, stream>>>(
      a_bf, WqkvT, bqkv, nullptr, nullptr, q_bf, k_bf, v_bf, NROWS, 1536, 512);
  // attention (1024 blocks, quarter-split waves)
  attn_kernel<<<1024, 256, 0, stream>>>(q_bf, k_bf, v_bf, E_bf, att_bf);
  // proj + residual -> y (fp32)
  gemm_bf16<64, 1><<<dim3(512 / 64, NROWS / 128), 256, 0, stream>>>(
      att_bf, WprojT, bproj, x, y, nullptr, nullptr, nullptr, NROWS, 512, 512);
  // LN2 (reuse a_bf as m_bf)
  ln_bf16_kernel<<<NROWS, 64, 0, stream>>>(y, g2, b2, a_bf);
  // FFN1 + gelu
  gemm_bf16<128, 2><<<dim3(2048 / 128, NROWS / 128), 256, 0, stream>>>(
      a_bf, W1T, bm1, nullptr, nullptr, h_bf, nullptr, nullptr, NROWS, 2048, 512);
  // FFN2 + residual -> out
  gemm_bf16<64, 3><<<dim3(512 / 64, NROWS / 128), 256, 0, stream>>>(
      h_bf, W2T, bm2, y, out, nullptr, nullptr, nullptr, NROWS, 512, 2048);
}

// Round 7
// 178.838 us; speedup vs baseline: 1.4005x; 1.3512x over previous
//
#include <hip/hip_runtime.h>
#include <math.h>

typedef unsigned short u16;
typedef unsigned int u32;
using short8 = __attribute__((ext_vector_type(8))) short;
using f32x4  = __attribute__((ext_vector_type(4))) float;

#define SEQ 2048
#define NH 8
#define DM 512
#define DH 64
#define NROWS 4096  // B*S
#define BATCH 2
#define KVB 128

__device__ __forceinline__ float bf2f(u16 u) {
  union { u32 i; float f; } c; c.i = ((u32)u) << 16; return c.f;
}
__device__ __forceinline__ u16 f2bf(float f) {
  union { float f; u32 i; } c; c.f = f;
  u32 r = c.i + 0x7fffu + ((c.i >> 16) & 1u);
  return (u16)(r >> 16);
}

// async global->LDS, 16B per lane. LDS dest must be wave-uniform base.
__device__ __forceinline__ void gll16(const u16* g, u16* l) {
  __builtin_amdgcn_global_load_lds(
      (const __attribute__((address_space(1))) u32*)g,
      (__attribute__((address_space(3))) u32*)l, 16, 0, 0);
}

// ---------------- LayerNorm (fp32 in -> bf16 out), one wave per 512-row ----
__global__ __launch_bounds__(64) void ln_bf16_kernel(
    const float* __restrict__ x, const float* __restrict__ gw,
    const float* __restrict__ bw, u16* __restrict__ out)
{
  int row = blockIdx.x;
  int lane = threadIdx.x;
  const float* xr = x + (size_t)row * DM;
  float4 v0 = ((const float4*)xr)[lane];
  float4 v1 = ((const float4*)xr)[lane + 64];
  float s  = v0.x + v0.y + v0.z + v0.w + v1.x + v1.y + v1.z + v1.w;
  float s2 = v0.x*v0.x + v0.y*v0.y + v0.z*v0.z + v0.w*v0.w
           + v1.x*v1.x + v1.y*v1.y + v1.z*v1.z + v1.w*v1.w;
  #pragma unroll
  for (int m = 1; m < 64; m <<= 1) {
    s  += __shfl_xor(s,  m);
    s2 += __shfl_xor(s2, m);
  }
  float mu   = s * (1.0f / DM);
  float var  = s2 * (1.0f / DM) - mu * mu;
  float rstd = rsqrtf(var + 1e-5f);
  float4 ga = ((const float4*)gw)[lane],      ba = ((const float4*)bw)[lane];
  float4 gb = ((const float4*)gw)[lane + 64], bb = ((const float4*)bw)[lane + 64];
  ushort4 o0, o1;
  o0.x = f2bf((v0.x - mu) * rstd * ga.x + ba.x);
  o0.y = f2bf((v0.y - mu) * rstd * ga.y + ba.y);
  o0.z = f2bf((v0.z - mu) * rstd * ga.z + ba.z);
  o0.w = f2bf((v0.w - mu) * rstd * ga.w + ba.w);
  o1.x = f2bf((v1.x - mu) * rstd * gb.x + bb.x);
  o1.y = f2bf((v1.y - mu) * rstd * gb.y + bb.y);
  o1.z = f2bf((v1.z - mu) * rstd * gb.z + bb.z);
  o1.w = f2bf((v1.w - mu) * rstd * gb.w + bb.w);
  *(ushort4*)&out[(size_t)row * DM + lane * 4]       = o0;
  *(ushort4*)&out[(size_t)row * DM + 256 + lane * 4] = o1;
}

// ---------------- Transpose + cast fp32 (K x N) -> bf16 (N x K) ------------
__global__ __launch_bounds__(256) void transpose_cast_kernel(
    const float* __restrict__ W, u16* __restrict__ Wt, int K, int N)
{
  __shared__ float tile[32][33];
  int bn = blockIdx.x * 32, bk = blockIdx.y * 32;
  int tx = threadIdx.x & 31, ty = threadIdx.x >> 5; // 32 x 8
  #pragma unroll
  for (int i = 0; i < 32; i += 8)
    tile[ty + i][tx] = W[(size_t)(bk + ty + i) * N + bn + tx];
  __syncthreads();
  #pragma unroll
  for (int i = 0; i < 32; i += 8)
    Wt[(size_t)(bn + ty + i) * K + bk + tx] = f2bf(tile[tx][ty + i]);
}

// ---------------- Elementwise cast fp32 -> bf16 ----------------------------
__global__ __launch_bounds__(256) void cast_bf16_kernel(
    const float* __restrict__ in, u16* __restrict__ out, int n)
{
  int i = (blockIdx.x * 256 + threadIdx.x) * 4;
  if (i >= n) return;
  float4 v = *(const float4*)&in[i];
  ushort4 o;
  o.x = f2bf(v.x); o.y = f2bf(v.y); o.z = f2bf(v.z); o.w = f2bf(v.w);
  *(ushort4*)&out[i] = o;
}

// ---------------- 128xTN MFMA GEMM, BK=64, double-buffered gll staging -----
// 1-D grid (nwg % 8 == 0), bijective XCD swizzle. Per K-step: issue next
// tile's global_load_lds FIRST, MFMA current buffer, then vmcnt(0)+barrier.
template<int TN, int MODE>
__global__ __launch_bounds__(256) void gemm_bf16(
    const u16* __restrict__ A, const u16* __restrict__ Bt,
    const float* __restrict__ bias, const float* __restrict__ res,
    float* __restrict__ outF, u16* __restrict__ outB0,
    u16* __restrict__ outB1, u16* __restrict__ outB2,
    int M, int N, int K)
{
  constexpr int NI = TN / 32;       // n-frags per wave
  __shared__ u16 sA[2][128 * 64];
  __shared__ u16 sB[2][TN * 64];
  int tid = threadIdx.x;
  int lane = tid & 63, wv = tid >> 6;
  int wm = wv >> 1, wn = wv & 1;
  int g = lane >> 4, l15 = lane & 15;

  int nwg = gridDim.x, lin = blockIdx.x;
  int qq = nwg >> 3;
  int wg = (lin & 7) * qq + (lin >> 3);     // bijective: nwg % 8 == 0
  int ntn = N / TN;
  int m0 = (wg / ntn) * 128, n0 = (wg % ntn) * TN;

  auto stage = [&](int buf, int k0) {
    #pragma unroll
    for (int s = 0; s < 4; ++s) {           // A: 128 rows x 8 chunks
      int c = s * 256 + tid;
      int row = c >> 3, p = c & 7;
      gll16(&A[(size_t)(m0 + row) * K + k0 + ((p ^ (row & 7)) * 8)],
            &sA[buf][(size_t)(s * 256 + wv * 64) * 8]);
    }
    #pragma unroll
    for (int s = 0; s < TN / 32; ++s) {     // B: TN rows x 8 chunks
      int c = s * 256 + tid;
      int row = c >> 3, p = c & 7;
      gll16(&Bt[(size_t)(n0 + row) * K + k0 + ((p ^ (row & 7)) * 8)],
            &sB[buf][(size_t)(s * 256 + wv * 64) * 8]);
    }
  };

  f32x4 acc[4][NI] = {};
  stage(0, 0);
  asm volatile("s_waitcnt vmcnt(0)" ::: "memory");
  __syncthreads();

  int nk = K / 64;
  for (int kt = 0; kt < nk; ++kt) {
    int cur = kt & 1;
    if (kt + 1 < nk) stage(cur ^ 1, (kt + 1) * 64);   // prefetch flies under MFMA
    #pragma unroll
    for (int kk = 0; kk < 2; ++kk) {
      short8 af[4], bfr[NI];
      #pragma unroll
      for (int i = 0; i < 4; ++i) {
        int row = wm * 64 + i * 16 + l15;
        af[i] = *(const short8*)&sA[cur][row * 64 + (((4 * kk + g) ^ (row & 7)) * 8)];
      }
      #pragma unroll
      for (int i = 0; i < NI; ++i) {
        int row = wn * (TN / 2) + i * 16 + l15;
        bfr[i] = *(const short8*)&sB[cur][row * 64 + (((4 * kk + g) ^ (row & 7)) * 8)];
      }
      #pragma unroll
      for (int mi = 0; mi < 4; ++mi)
        #pragma unroll
        for (int ni = 0; ni < NI; ++ni)
          acc[mi][ni] = __builtin_amdgcn_mfma_f32_16x16x32_bf16(af[mi], bfr[ni], acc[mi][ni], 0, 0, 0);
    }
    asm volatile("s_waitcnt vmcnt(0)" ::: "memory");
    __syncthreads();
  }

  #pragma unroll
  for (int mi = 0; mi < 4; ++mi) {
    #pragma unroll
    for (int ni = 0; ni < NI; ++ni) {
      #pragma unroll
      for (int r = 0; r < 4; ++r) {
        int grow = m0 + wm * 64 + mi * 16 + g * 4 + r;
        int gcol = n0 + wn * (TN / 2) + ni * 16 + l15;
        float val = acc[mi][ni][r] + bias[gcol];
        if (MODE == 0) {
          int part = gcol >> 9, c = gcol & 511;
          int hh = c >> 6, dd = c & 63;
          int bb = grow >> 11, ss = grow & 2047;
          size_t dst = (((size_t)(bb * NH + hh)) * SEQ + ss) * DH + dd;
          if (part == 0)      outB0[dst] = f2bf(val * 0.18033688011112042f); // q * 0.125*log2(e)
          else if (part == 1) outB1[dst] = f2bf(val);           // k
          else                outB2[dst] = f2bf(val);           // v
        } else if (MODE == 1 || MODE == 3) {
          size_t idx = (size_t)grow * DM + gcol;
          outF[idx] = val + res[idx];
        } else { // MODE 2: gelu (tanh approx = jax.nn.gelu default)
          float t = val;
          float inner = 0.7978845608028654f * (t + 0.044715f * t * t * t);
          float gl = 0.5f * t * (1.0f + tanhf(inner));
          outB0[(size_t)grow * N + gcol] = f2bf(gl);
        }
      }
    }
  }
}

// ---------------- Flash causal attention with relative positions -----------
// R4 structure (best measured: 86us). 512 blocks (2/CU): block = (bh, pp)
// handles fold pair of 32-row q-tiles (pp, 63-pp): always exactly 17
// iterations of KVB=128. 4 waves = 2 row-groups x 2 column-halves; online
// softmax shared across column halves via LDS; O-halves combined at flush.
__global__ __launch_bounds__(256, 2) void attn_kernel(
    const u16* __restrict__ Q, const u16* __restrict__ Kb,
    const u16* __restrict__ Vb, const u16* __restrict__ Eb,
    u16* __restrict__ Ob)
{
  __shared__ u16 sK[2][KVB * 64];        // 32KB, chunk-swizzled linear (gll)
  __shared__ u16 sV[64 * (KVB + 8)];     // 17.4KB, [d][t] block-XOR, single
  __shared__ u16 sP[4][16 * 64];         // 8KB, per-wave (sO overlays)
  __shared__ float sM[2][32];            // cross-half max exchange
  __shared__ float sS[2][32];            // cross-half sum exchange

  int tid = threadIdx.x, lane = tid & 63, wv = tid >> 6;
  int wr = wv & 1, wc = wv >> 1;
  int g = lane >> 4, l15 = lane & 15;
  int blk = blockIdx.x;
  int bh = blk >> 5, pp = blk & 31;
  int hh = bh & (NH - 1), bb = bh >> 3;

  const u16* Qh = Q  + (size_t)bh * SEQ * DH;
  const u16* Kh = Kb + (size_t)bh * SEQ * DH;
  const u16* Vh = Vb + (size_t)bh * SEQ * DH;
  const u16* Eh = Eb + (size_t)hh * SEQ * DH;

  int tileA = pp, tileB = 63 - pp;
  int itersA = pp / 4 + 1;
  const int TOT = 17;

  int rstage = tid >> 3, cstage = (tid & 7) * 8;

  // ---- prologue: stage kt=0 ----
  #pragma unroll
  for (int s = 0; s < 4; ++s) {
    int c = s * 256 + tid, t = c >> 3, pc = c & 7;
    gll16(&Kh[(size_t)t * DH + ((pc ^ (t & 7)) * 8)],
          &sK[0][(size_t)(s * 256 + wv * 64) * 8]);
  }
  #pragma unroll
  for (int q = 0; q < 4; ++q) {
    int t = q * 32 + rstage;
    short8 vv = *(const short8*)&Vh[(size_t)t * DH + cstage];
    #pragma unroll
    for (int j = 0; j < 8; ++j) {
      int d = cstage + j;
      sV[d * (KVB + 8) + (((t >> 3) ^ (d >> 3)) * 8) + (t & 7)] = (u16)vv[j];
    }
  }
  asm volatile("s_waitcnt vmcnt(0)" ::: "memory");
  __syncthreads();

  short8 qf[2];
  {
    int sw = tileA * 32 + wr * 16;
    qf[0] = *(const short8*)&Qh[(size_t)(sw + l15) * DH + g * 8];
    qf[1] = *(const short8*)&Qh[(size_t)(sw + l15) * DH + g * 8 + 32];
  }
  f32x4 o[4] = {};
  float mrow[4] = {-1e30f, -1e30f, -1e30f, -1e30f};
  float lsum[4] = {};

  float* sO = (float*)&sP[0][0];   // [2][16][64] f32 overlay at flush time

  auto flushOut = [&](int tile) {
    int swt = tile * 32 + wr * 16;
    if (wc == 1) {
      #pragma unroll
      for (int r = 0; r < 4; ++r) {
        float rl = 1.0f / lsum[r];
        #pragma unroll
        for (int nb = 0; nb < 4; ++nb)
          sO[wr * 1024 + (g * 4 + r) * 64 + nb * 16 + l15] = o[nb][r] * rl;
      }
    }
    __syncthreads();
    if (wc == 0) {
      #pragma unroll
      for (int r = 0; r < 4; ++r) {
        float rl = 1.0f / lsum[r];
        int ss = swt + g * 4 + r;
        #pragma unroll
        for (int nb = 0; nb < 4; ++nb) {
          float val = o[nb][r] * rl + sO[wr * 1024 + (g * 4 + r) * 64 + nb * 16 + l15];
          Ob[((size_t)(bb * SEQ + ss)) * DM + hh * DH + nb * 16 + l15] = f2bf(val);
        }
      }
    }
  };

  for (int it = 0; it < TOT; ++it) {
    int cur = it & 1;
    if (it == itersA) {
      flushOut(tileA);
      #pragma unroll
      for (int nb = 0; nb < 4; ++nb) o[nb] = f32x4{};
      #pragma unroll
      for (int r = 0; r < 4; ++r) { mrow[r] = -1e30f; lsum[r] = 0.f; }
      int sw = tileB * 32 + wr * 16;
      qf[0] = *(const short8*)&Qh[(size_t)(sw + l15) * DH + g * 8];
      qf[1] = *(const short8*)&Qh[(size_t)(sw + l15) * DH + g * 8 + 32];
    }
    int tile = (it < itersA) ? tileA : tileB;
    int kt   = (it < itersA) ? it : it - itersA;
    int sw = tile * 32 + wr * 16, t0 = kt * KVB;

    // prefetch next K (async->LDS) and V (->regs)
    bool pre = (it + 1 < TOT);
    short8 vp[4];
    if (pre) {
      int kn = (it + 1 < itersA) ? it + 1 : it + 1 - itersA;
      int tb = kn * KVB;
      #pragma unroll
      for (int s = 0; s < 4; ++s) {
        int c = s * 256 + tid, t = c >> 3, pc = c & 7;
        gll16(&Kh[(size_t)(tb + t) * DH + ((pc ^ (t & 7)) * 8)],
              &sK[cur ^ 1][(size_t)(s * 256 + wv * 64) * 8]);
      }
      #pragma unroll
      for (int q = 0; q < 4; ++q)
        vp[q] = *(const short8*)&Vh[(size_t)(tb + q * 32 + rstage) * DH + cstage];
    }

    // S1 = Q K^T (16 rows x 64 cols per wave, this wave's column half)
    f32x4 accS[4];
    #pragma unroll
    for (int ni = 0; ni < 4; ++ni) {
      int row = wc * 64 + ni * 16 + l15;
      short8 k0 = *(const short8*)&sK[cur][row * 64 + ((g ^ (row & 7)) * 8)];
      short8 k1 = *(const short8*)&sK[cur][row * 64 + (((4 + g) ^ (row & 7)) * 8)];
      f32x4 z = {};
      z = __builtin_amdgcn_mfma_f32_16x16x32_bf16(qf[0], k0, z, 0, 0, 0);
      z = __builtin_amdgcn_mfma_f32_16x16x32_bf16(qf[1], k1, z, 0, 0, 0);
      accS[ni] = z;
    }

    // S2 = Q E^T strip (16 x 80): rel[s,t] = q[s].E[2047 - s + t]
    int jbase = 2032 - sw + t0 + wc * 64;
    f32x4 accR[5];
    #pragma unroll
    for (int nb = 0; nb < 5; ++nb) {
      int j = jbase + nb * 16 + l15; if (j > 2047) j = 2047;
      short8 e0 = *(const short8*)&Eh[(size_t)j * DH + g * 8];
      short8 e1 = *(const short8*)&Eh[(size_t)j * DH + 32 + g * 8];
      f32x4 z = {};
      z = __builtin_amdgcn_mfma_f32_16x16x32_bf16(qf[0], e0, z, 0, 0, 0);
      z = __builtin_amdgcn_mfma_f32_16x16x32_bf16(qf[1], e1, z, 0, 0, 0);
      accR[nb] = z;
    }

    // skew realign + combine + causal mask
    bool needMask = (t0 + wc * 64 + 63 > sw);
    #pragma unroll
    for (int r = 0; r < 4; ++r) {
      int srow = g * 4 + r;
      int dsh = 15 - srow + l15;                 // 0..30
      int srcl = (lane & 48) + (dsh & 15);
      float sh[5];
      #pragma unroll
      for (int nb = 0; nb < 5; ++nb) sh[nb] = __shfl(accR[nb][r], srcl);
      bool cy = dsh >= 16;
      #pragma unroll
      for (int ni = 0; ni < 4; ++ni) {
        float rel = cy ? sh[ni + 1] : sh[ni];
        float val = accS[ni][r] + rel;
        if (needMask && (t0 + wc * 64 + ni * 16 + l15 > sw + srow)) val = -1e30f;
        accS[ni][r] = val;
      }
    }

    // local row max -> exchange across column halves
    float lmax[4];
    #pragma unroll
    for (int r = 0; r < 4; ++r) {
      float tm = fmaxf(fmaxf(accS[0][r], accS[1][r]), fmaxf(accS[2][r], accS[3][r]));
      tm = fmaxf(tm, __shfl_xor(tm, 1));
      tm = fmaxf(tm, __shfl_xor(tm, 2));
      tm = fmaxf(tm, __shfl_xor(tm, 4));
      tm = fmaxf(tm, __shfl_xor(tm, 8));
      lmax[r] = tm;
    }
    if (l15 == 0) {
      #pragma unroll
      for (int r = 0; r < 4; ++r) sM[wc][wr * 16 + g * 4 + r] = lmax[r];
    }
    __syncthreads();                              // B1
    float4 om = *(float4*)&sM[wc ^ 1][wr * 16 + g * 4];

    // global max -> rescale o, exp, local sums
    float sesav[4], lscl[4];
    #pragma unroll
    for (int r = 0; r < 4; ++r) {
      float gm = fmaxf(lmax[r], ((float*)&om)[r]);
      float mnew = fmaxf(mrow[r], gm);
      lscl[r] = exp2f(mrow[r] - mnew);
      mrow[r] = mnew;
      float se = 0.f;
      #pragma unroll
      for (int ni = 0; ni < 4; ++ni) {
        float pe = exp2f(accS[ni][r] - mnew);
        accS[ni][r] = pe;
        se += pe;
      }
      se += __shfl_xor(se, 1); se += __shfl_xor(se, 2);
      se += __shfl_xor(se, 4); se += __shfl_xor(se, 8);
      sesav[r] = se;
      o[0][r] *= lscl[r]; o[1][r] *= lscl[r]; o[2][r] *= lscl[r]; o[3][r] *= lscl[r];
    }
    if (l15 == 0) {
      #pragma unroll
      for (int r = 0; r < 4; ++r) sS[wc][wr * 16 + g * 4 + r] = sesav[r];
    }

    // P -> per-wave LDS, then PV (accumulates into rescaled o)
    #pragma unroll
    for (int ni = 0; ni < 4; ++ni)
      #pragma unroll
      for (int r = 0; r < 4; ++r) {
        int srow = g * 4 + r;
        int chunk = (ni * 2 + (l15 >> 3)) ^ (srow & 7);
        sP[wv][srow * 64 + chunk * 8 + (l15 & 7)] = f2bf(accS[ni][r]);
      }
    asm volatile("s_waitcnt lgkmcnt(0)" ::: "memory");
    __builtin_amdgcn_sched_barrier(0);
    #pragma unroll
    for (int kk = 0; kk < 2; ++kk) {
      short8 pf = *(const short8*)&sP[wv][l15 * 64 + (((kk * 4 + g) ^ (l15 & 7)) * 8)];
      #pragma unroll
      for (int nb = 0; nb < 4; ++nb) {
        int d = nb * 16 + l15;
        int ck = wc * 8 + kk * 4 + g;
        short8 vf = *(const short8*)&sV[d * (KVB + 8) + ((ck ^ (d >> 3)) * 8)];
        o[nb] = __builtin_amdgcn_mfma_f32_16x16x32_bf16(pf, vf, o[nb], 0, 0, 0);
      }
    }

    __syncthreads();                              // B2 (drains vm+lgkm)
    float4 os = *(float4*)&sS[wc ^ 1][wr * 16 + g * 4];
    #pragma unroll
    for (int r = 0; r < 4; ++r)
      lsum[r] = lsum[r] * lscl[r] + sesav[r] + ((float*)&os)[r];

    // write prefetched V^T into sV (reads of this iter are done; next
    // iteration's B1 orders these writes before its PV reads)
    if (pre) {
      #pragma unroll
      for (int q = 0; q < 4; ++q) {
        int t = q * 32 + rstage;
        #pragma unroll
        for (int j = 0; j < 8; ++j) {
          int d = cstage + j;
          sV[d * (KVB + 8) + (((t >> 3) ^ (d >> 3)) * 8) + (t & 7)] = (u16)vp[q][j];
        }
      }
    }
  }

  flushOut(tileB);
}

// ---------------------------------------------------------------------------
extern "C" void kernel_launch(void* const* d_in, const int* in_sizes, int n_in,
                              void* d_out, int out_size, void* d_ws, size_t ws_size,
                              hipStream_t stream) {
  const float* x     = (const float*)d_in[0];
  // d_in[1] = mask: recomputed causally in-kernel
  const float* Wqkv  = (const float*)d_in[2];
  const float* bqkv  = (const float*)d_in[3];
  const float* Wproj = (const float*)d_in[4];
  const float* bproj = (const float*)d_in[5];
  const float* E     = (const float*)d_in[6];
  const float* g1    = (const float*)d_in[7];
  const float* b1    = (const float*)d_in[8];
  const float* g2    = (const float*)d_in[9];
  const float* b2    = (const float*)d_in[10];
  const float* W1    = (const float*)d_in[11];
  const float* bm1   = (const float*)d_in[12];
  const float* W2    = (const float*)d_in[13];
  const float* bm2   = (const float*)d_in[14];
  float* out = (float*)d_out;

  char* ws = (char*)d_ws;
  size_t off = 0;
  auto alloc = [&](size_t bytes) {
    void* p = ws + off;
    off += (bytes + 255) & ~(size_t)255;
    return p;
  };
  u16* a_bf   = (u16*)alloc((size_t)NROWS * DM * 2);      // LN1 out, reused for LN2 out
  u16* q_bf   = (u16*)alloc((size_t)NROWS * DM * 2);
  u16* k_bf   = (u16*)alloc((size_t)NROWS * DM * 2);
  u16* v_bf   = (u16*)alloc((size_t)NROWS * DM * 2);
  u16* att_bf = (u16*)alloc((size_t)NROWS * DM * 2);
  float* y    = (float*)alloc((size_t)NROWS * DM * 4);
  u16* h_bf   = (u16*)alloc((size_t)NROWS * 2048 * 2);
  u16* WqkvT  = (u16*)alloc((size_t)1536 * 512 * 2);
  u16* WprojT = (u16*)alloc((size_t)512 * 512 * 2);
  u16* W1T    = (u16*)alloc((size_t)2048 * 512 * 2);
  u16* W2T    = (u16*)alloc((size_t)512 * 2048 * 2);
  u16* E_bf   = (u16*)alloc((size_t)NH * SEQ * DH * 2);

  // weights -> bf16 (transposed to N x K)
  transpose_cast_kernel<<<dim3(1536 / 32, 512 / 32), 256, 0, stream>>>(Wqkv, WqkvT, 512, 1536);
  transpose_cast_kernel<<<dim3(512 / 32, 512 / 32), 256, 0, stream>>>(Wproj, WprojT, 512, 512);
  transpose_cast_kernel<<<dim3(2048 / 32, 512 / 32), 256, 0, stream>>>(W1, W1T, 512, 2048);
  transpose_cast_kernel<<<dim3(512 / 32, 2048 / 32), 256, 0, stream>>>(W2, W2T, 2048, 512);
  cast_bf16_kernel<<<(NH * SEQ * DH) / (256 * 4), 256, 0, stream>>>(E, E_bf, NH * SEQ * DH);

  // LN1
  ln_bf16_kernel<<<NROWS, 64, 0, stream>>>(x, g1, b1, a_bf);
  // QKV (q pre-scaled by 0.125*log2e for exp2-softmax); grid 384 = 32x12
  gemm_bf16<128, 0><<<(NROWS / 128) * (1536 / 128), 256, 0, stream>>>(
      a_bf, WqkvT, bqkv, nullptr, nullptr, q_bf, k_bf, v_bf, NROWS, 1536, 512);
  // attention (R4 structure: balanced fold, 512 blocks)
  attn_kernel<<<512, 256, 0, stream>>>(q_bf, k_bf, v_bf, E_bf, att_bf);
  // proj + residual -> y (fp32); grid 256 = 32x8
  gemm_bf16<64, 1><<<(NROWS / 128) * (512 / 64), 256, 0, stream>>>(
      att_bf, WprojT, bproj, x, y, nullptr, nullptr, nullptr, NROWS, 512, 512);
  // LN2 (reuse a_bf as m_bf)
  ln_bf16_kernel<<<NROWS, 64, 0, stream>>>(y, g2, b2, a_bf);
  // FFN1 + gelu; grid 512 = 32x16
  gemm_bf16<128, 2><<<(NROWS / 128) * (2048 / 128), 256, 0, stream>>>(
      a_bf, W1T, bm1, nullptr, nullptr, h_bf, nullptr, nullptr, NROWS, 2048, 512);
  // FFN2 + residual -> out; grid 256 = 32x8
  gemm_bf16<64, 3><<<(NROWS / 128) * (512 / 64), 256, 0, stream>>>(
      h_bf, W2T, bm2, y, out, nullptr, nullptr, nullptr, NROWS, 512, 2048);
}

// Round 8
// 171.734 us; speedup vs baseline: 1.4584x; 1.0414x over previous
//
#include <hip/hip_runtime.h>
#include <math.h>

typedef unsigned short u16;
typedef unsigned int u32;
using short8 = __attribute__((ext_vector_type(8))) short;
using f32x4  = __attribute__((ext_vector_type(4))) float;

#define SEQ 2048
#define NH 8
#define DM 512
#define DH 64
#define NROWS 4096  // B*S
#define BATCH 2
#define KVB 128

__device__ __forceinline__ float bf2f(u16 u) {
  union { u32 i; float f; } c; c.i = ((u32)u) << 16; return c.f;
}
__device__ __forceinline__ u16 f2bf(float f) {
  union { float f; u32 i; } c; c.f = f;
  u32 r = c.i + 0x7fffu + ((c.i >> 16) & 1u);
  return (u16)(r >> 16);
}

// async global->LDS, 16B per lane. LDS dest must be wave-uniform base.
__device__ __forceinline__ void gll16(const u16* g, u16* l) {
  __builtin_amdgcn_global_load_lds(
      (const __attribute__((address_space(1))) u32*)g,
      (__attribute__((address_space(3))) u32*)l, 16, 0, 0);
}

template<int N> __device__ __forceinline__ void waitcnt_vm() {
  if constexpr (N == 0)      asm volatile("s_waitcnt vmcnt(0)" ::: "memory");
  else if constexpr (N == 4) asm volatile("s_waitcnt vmcnt(4)" ::: "memory");
  else if constexpr (N == 6) asm volatile("s_waitcnt vmcnt(6)" ::: "memory");
  else if constexpr (N == 8) asm volatile("s_waitcnt vmcnt(8)" ::: "memory");
}

// ---------------- LayerNorm (fp32 in -> bf16 out), one wave per 512-row ----
__global__ __launch_bounds__(64) void ln_bf16_kernel(
    const float* __restrict__ x, const float* __restrict__ gw,
    const float* __restrict__ bw, u16* __restrict__ out)
{
  int row = blockIdx.x;
  int lane = threadIdx.x;
  const float* xr = x + (size_t)row * DM;
  float4 v0 = ((const float4*)xr)[lane];
  float4 v1 = ((const float4*)xr)[lane + 64];
  float s  = v0.x + v0.y + v0.z + v0.w + v1.x + v1.y + v1.z + v1.w;
  float s2 = v0.x*v0.x + v0.y*v0.y + v0.z*v0.z + v0.w*v0.w
           + v1.x*v1.x + v1.y*v1.y + v1.z*v1.z + v1.w*v1.w;
  #pragma unroll
  for (int m = 1; m < 64; m <<= 1) {
    s  += __shfl_xor(s,  m);
    s2 += __shfl_xor(s2, m);
  }
  float mu   = s * (1.0f / DM);
  float var  = s2 * (1.0f / DM) - mu * mu;
  float rstd = rsqrtf(var + 1e-5f);
  float4 ga = ((const float4*)gw)[lane],      ba = ((const float4*)bw)[lane];
  float4 gb = ((const float4*)gw)[lane + 64], bb = ((const float4*)bw)[lane + 64];
  ushort4 o0, o1;
  o0.x = f2bf((v0.x - mu) * rstd * ga.x + ba.x);
  o0.y = f2bf((v0.y - mu) * rstd * ga.y + ba.y);
  o0.z = f2bf((v0.z - mu) * rstd * ga.z + ba.z);
  o0.w = f2bf((v0.w - mu) * rstd * ga.w + ba.w);
  o1.x = f2bf((v1.x - mu) * rstd * gb.x + bb.x);
  o1.y = f2bf((v1.y - mu) * rstd * gb.y + bb.y);
  o1.z = f2bf((v1.z - mu) * rstd * gb.z + bb.z);
  o1.w = f2bf((v1.w - mu) * rstd * gb.w + bb.w);
  *(ushort4*)&out[(size_t)row * DM + lane * 4]       = o0;
  *(ushort4*)&out[(size_t)row * DM + 256 + lane * 4] = o1;
}

// ---------------- Transpose + cast fp32 (K x N) -> bf16 (N x K) ------------
__global__ __launch_bounds__(256) void transpose_cast_kernel(
    const float* __restrict__ W, u16* __restrict__ Wt, int K, int N)
{
  __shared__ float tile[32][33];
  int bn = blockIdx.x * 32, bk = blockIdx.y * 32;
  int tx = threadIdx.x & 31, ty = threadIdx.x >> 5; // 32 x 8
  #pragma unroll
  for (int i = 0; i < 32; i += 8)
    tile[ty + i][tx] = W[(size_t)(bk + ty + i) * N + bn + tx];
  __syncthreads();
  #pragma unroll
  for (int i = 0; i < 32; i += 8)
    Wt[(size_t)(bn + ty + i) * K + bk + tx] = f2bf(tile[tx][ty + i]);
}

// ---------------- Elementwise cast fp32 -> bf16 ----------------------------
__global__ __launch_bounds__(256) void cast_bf16_kernel(
    const float* __restrict__ in, u16* __restrict__ out, int n)
{
  int i = (blockIdx.x * 256 + threadIdx.x) * 4;
  if (i >= n) return;
  float4 v = *(const float4*)&in[i];
  ushort4 o;
  o.x = f2bf(v.x); o.y = f2bf(v.y); o.z = f2bf(v.z); o.w = f2bf(v.w);
  *(ushort4*)&out[i] = o;
}

// ---------------- TMxTN MFMA GEMM, BK=64, counted-vmcnt 2-phase pipeline ---
// 1-D grid (nwg % 8 == 0), bijective XCD swizzle. Per K-step:
// barrier -> stage(next buf) -> vmcnt(LOADS) [waits PREVIOUS stage only]
// -> barrier -> MFMA(cur buf). Never drains the in-flight prefetch.
template<int TM, int TN, int MODE>
__global__ __launch_bounds__(256) void gemm_bf16(
    const u16* __restrict__ A, const u16* __restrict__ Bt,
    const float* __restrict__ bias, const float* __restrict__ res,
    float* __restrict__ outF, u16* __restrict__ outB0,
    u16* __restrict__ outB1, u16* __restrict__ outB2,
    int M, int N, int K)
{
  constexpr int MI = TM / 32;       // m-frags per wave
  constexpr int NI = TN / 32;       // n-frags per wave
  constexpr int LOADS = TM / 32 + TN / 32;  // gll16 per thread per stage
  __shared__ u16 sA[2][TM * 64];
  __shared__ u16 sB[2][TN * 64];
  int tid = threadIdx.x;
  int lane = tid & 63, wv = tid >> 6;
  int wm = wv >> 1, wn = wv & 1;
  int g = lane >> 4, l15 = lane & 15;

  int nwg = gridDim.x, lin = blockIdx.x;
  int qq = nwg >> 3;
  int wg = (lin & 7) * qq + (lin >> 3);     // bijective: nwg % 8 == 0
  int ntn = N / TN;
  int m0 = (wg / ntn) * TM, n0 = (wg % ntn) * TN;

  auto stage = [&](int buf, int k0) {
    #pragma unroll
    for (int s = 0; s < TM / 32; ++s) {     // A: TM rows x 8 chunks
      int c = s * 256 + tid;
      int row = c >> 3, p = c & 7;
      gll16(&A[(size_t)(m0 + row) * K + k0 + ((p ^ (row & 7)) * 8)],
            &sA[buf][(size_t)(s * 256 + wv * 64) * 8]);
    }
    #pragma unroll
    for (int s = 0; s < TN / 32; ++s) {     // B: TN rows x 8 chunks
      int c = s * 256 + tid;
      int row = c >> 3, p = c & 7;
      gll16(&Bt[(size_t)(n0 + row) * K + k0 + ((p ^ (row & 7)) * 8)],
            &sB[buf][(size_t)(s * 256 + wv * 64) * 8]);
    }
  };

  f32x4 acc[MI][NI] = {};
  stage(0, 0);

  int nk = K / 64;
  for (int kt = 0; kt < nk; ++kt) {
    int cur = kt & 1;
    __syncthreads();                         // buf cur^1 reads (prev compute) done
    if (kt + 1 < nk) {
      stage(cur ^ 1, (kt + 1) * 64);         // prefetch into freed buffer
      waitcnt_vm<LOADS>();                   // wait only for PREVIOUS stage
    } else {
      waitcnt_vm<0>();
    }
    __syncthreads();                         // buf cur visible to all waves
    #pragma unroll
    for (int kk = 0; kk < 2; ++kk) {
      short8 af[MI], bfr[NI];
      #pragma unroll
      for (int i = 0; i < MI; ++i) {
        int row = wm * (TM / 2) + i * 16 + l15;
        af[i] = *(const short8*)&sA[cur][row * 64 + (((4 * kk + g) ^ (row & 7)) * 8)];
      }
      #pragma unroll
      for (int i = 0; i < NI; ++i) {
        int row = wn * (TN / 2) + i * 16 + l15;
        bfr[i] = *(const short8*)&sB[cur][row * 64 + (((4 * kk + g) ^ (row & 7)) * 8)];
      }
      #pragma unroll
      for (int mi = 0; mi < MI; ++mi)
        #pragma unroll
        for (int ni = 0; ni < NI; ++ni)
          acc[mi][ni] = __builtin_amdgcn_mfma_f32_16x16x32_bf16(af[mi], bfr[ni], acc[mi][ni], 0, 0, 0);
    }
  }

  #pragma unroll
  for (int mi = 0; mi < MI; ++mi) {
    #pragma unroll
    for (int ni = 0; ni < NI; ++ni) {
      #pragma unroll
      for (int r = 0; r < 4; ++r) {
        int grow = m0 + wm * (TM / 2) + mi * 16 + g * 4 + r;
        int gcol = n0 + wn * (TN / 2) + ni * 16 + l15;
        float val = acc[mi][ni][r] + bias[gcol];
        if (MODE == 0) {
          int part = gcol >> 9, c = gcol & 511;
          int hh = c >> 6, dd = c & 63;
          int bb = grow >> 11, ss = grow & 2047;
          size_t dst = (((size_t)(bb * NH + hh)) * SEQ + ss) * DH + dd;
          if (part == 0)      outB0[dst] = f2bf(val * 0.18033688011112042f); // q * 0.125*log2(e)
          else if (part == 1) outB1[dst] = f2bf(val);           // k
          else                outB2[dst] = f2bf(val);           // v
        } else if (MODE == 1 || MODE == 3) {
          size_t idx = (size_t)grow * DM + gcol;
          outF[idx] = val + res[idx];
        } else { // MODE 2: gelu (tanh approx = jax.nn.gelu default)
          float t = val;
          float inner = 0.7978845608028654f * (t + 0.044715f * t * t * t);
          float gl = 0.5f * t * (1.0f + tanhf(inner));
          outB0[(size_t)grow * N + gcol] = f2bf(gl);
        }
      }
    }
  }
}

// ---------------- Flash causal attention with relative positions -----------
// R4 structure (best measured: 86us). 512 blocks (2/CU): block = (bh, pp)
// handles fold pair of 32-row q-tiles (pp, 63-pp): always exactly 17
// iterations of KVB=128. 4 waves = 2 row-groups x 2 column-halves; online
// softmax shared across column halves via LDS; O-halves combined at flush.
__global__ __launch_bounds__(256, 2) void attn_kernel(
    const u16* __restrict__ Q, const u16* __restrict__ Kb,
    const u16* __restrict__ Vb, const u16* __restrict__ Eb,
    u16* __restrict__ Ob)
{
  __shared__ u16 sK[2][KVB * 64];        // 32KB, chunk-swizzled linear (gll)
  __shared__ u16 sV[64 * (KVB + 8)];     // 17.4KB, [d][t] block-XOR, single
  __shared__ u16 sP[4][16 * 64];         // 8KB, per-wave (sO overlays)
  __shared__ float sM[2][32];            // cross-half max exchange
  __shared__ float sS[2][32];            // cross-half sum exchange

  int tid = threadIdx.x, lane = tid & 63, wv = tid >> 6;
  int wr = wv & 1, wc = wv >> 1;
  int g = lane >> 4, l15 = lane & 15;
  int blk = blockIdx.x;
  int bh = blk >> 5, pp = blk & 31;
  int hh = bh & (NH - 1), bb = bh >> 3;

  const u16* Qh = Q  + (size_t)bh * SEQ * DH;
  const u16* Kh = Kb + (size_t)bh * SEQ * DH;
  const u16* Vh = Vb + (size_t)bh * SEQ * DH;
  const u16* Eh = Eb + (size_t)hh * SEQ * DH;

  int tileA = pp, tileB = 63 - pp;
  int itersA = pp / 4 + 1;
  const int TOT = 17;

  int rstage = tid >> 3, cstage = (tid & 7) * 8;

  // ---- prologue: stage kt=0 ----
  #pragma unroll
  for (int s = 0; s < 4; ++s) {
    int c = s * 256 + tid, t = c >> 3, pc = c & 7;
    gll16(&Kh[(size_t)t * DH + ((pc ^ (t & 7)) * 8)],
          &sK[0][(size_t)(s * 256 + wv * 64) * 8]);
  }
  #pragma unroll
  for (int q = 0; q < 4; ++q) {
    int t = q * 32 + rstage;
    short8 vv = *(const short8*)&Vh[(size_t)t * DH + cstage];
    #pragma unroll
    for (int j = 0; j < 8; ++j) {
      int d = cstage + j;
      sV[d * (KVB + 8) + (((t >> 3) ^ (d >> 3)) * 8) + (t & 7)] = (u16)vv[j];
    }
  }
  asm volatile("s_waitcnt vmcnt(0)" ::: "memory");
  __syncthreads();

  short8 qf[2];
  {
    int sw = tileA * 32 + wr * 16;
    qf[0] = *(const short8*)&Qh[(size_t)(sw + l15) * DH + g * 8];
    qf[1] = *(const short8*)&Qh[(size_t)(sw + l15) * DH + g * 8 + 32];
  }
  f32x4 o[4] = {};
  float mrow[4] = {-1e30f, -1e30f, -1e30f, -1e30f};
  float lsum[4] = {};

  float* sO = (float*)&sP[0][0];   // [2][16][64] f32 overlay at flush time

  auto flushOut = [&](int tile) {
    int swt = tile * 32 + wr * 16;
    if (wc == 1) {
      #pragma unroll
      for (int r = 0; r < 4; ++r) {
        float rl = 1.0f / lsum[r];
        #pragma unroll
        for (int nb = 0; nb < 4; ++nb)
          sO[wr * 1024 + (g * 4 + r) * 64 + nb * 16 + l15] = o[nb][r] * rl;
      }
    }
    __syncthreads();
    if (wc == 0) {
      #pragma unroll
      for (int r = 0; r < 4; ++r) {
        float rl = 1.0f / lsum[r];
        int ss = swt + g * 4 + r;
        #pragma unroll
        for (int nb = 0; nb < 4; ++nb) {
          float val = o[nb][r] * rl + sO[wr * 1024 + (g * 4 + r) * 64 + nb * 16 + l15];
          Ob[((size_t)(bb * SEQ + ss)) * DM + hh * DH + nb * 16 + l15] = f2bf(val);
        }
      }
    }
  };

  for (int it = 0; it < TOT; ++it) {
    int cur = it & 1;
    if (it == itersA) {
      flushOut(tileA);
      #pragma unroll
      for (int nb = 0; nb < 4; ++nb) o[nb] = f32x4{};
      #pragma unroll
      for (int r = 0; r < 4; ++r) { mrow[r] = -1e30f; lsum[r] = 0.f; }
      int sw = tileB * 32 + wr * 16;
      qf[0] = *(const short8*)&Qh[(size_t)(sw + l15) * DH + g * 8];
      qf[1] = *(const short8*)&Qh[(size_t)(sw + l15) * DH + g * 8 + 32];
    }
    int tile = (it < itersA) ? tileA : tileB;
    int kt   = (it < itersA) ? it : it - itersA;
    int sw = tile * 32 + wr * 16, t0 = kt * KVB;

    // prefetch next K (async->LDS) and V (->regs)
    bool pre = (it + 1 < TOT);
    short8 vp[4];
    if (pre) {
      int kn = (it + 1 < itersA) ? it + 1 : it + 1 - itersA;
      int tb = kn * KVB;
      #pragma unroll
      for (int s = 0; s < 4; ++s) {
        int c = s * 256 + tid, t = c >> 3, pc = c & 7;
        gll16(&Kh[(size_t)(tb + t) * DH + ((pc ^ (t & 7)) * 8)],
              &sK[cur ^ 1][(size_t)(s * 256 + wv * 64) * 8]);
      }
      #pragma unroll
      for (int q = 0; q < 4; ++q)
        vp[q] = *(const short8*)&Vh[(size_t)(tb + q * 32 + rstage) * DH + cstage];
    }

    // S1 = Q K^T (16 rows x 64 cols per wave, this wave's column half)
    f32x4 accS[4];
    #pragma unroll
    for (int ni = 0; ni < 4; ++ni) {
      int row = wc * 64 + ni * 16 + l15;
      short8 k0 = *(const short8*)&sK[cur][row * 64 + ((g ^ (row & 7)) * 8)];
      short8 k1 = *(const short8*)&sK[cur][row * 64 + (((4 + g) ^ (row & 7)) * 8)];
      f32x4 z = {};
      z = __builtin_amdgcn_mfma_f32_16x16x32_bf16(qf[0], k0, z, 0, 0, 0);
      z = __builtin_amdgcn_mfma_f32_16x16x32_bf16(qf[1], k1, z, 0, 0, 0);
      accS[ni] = z;
    }

    // S2 = Q E^T strip (16 x 80): rel[s,t] = q[s].E[2047 - s + t]
    int jbase = 2032 - sw + t0 + wc * 64;
    f32x4 accR[5];
    #pragma unroll
    for (int nb = 0; nb < 5; ++nb) {
      int j = jbase + nb * 16 + l15; if (j > 2047) j = 2047;
      short8 e0 = *(const short8*)&Eh[(size_t)j * DH + g * 8];
      short8 e1 = *(const short8*)&Eh[(size_t)j * DH + 32 + g * 8];
      f32x4 z = {};
      z = __builtin_amdgcn_mfma_f32_16x16x32_bf16(qf[0], e0, z, 0, 0, 0);
      z = __builtin_amdgcn_mfma_f32_16x16x32_bf16(qf[1], e1, z, 0, 0, 0);
      accR[nb] = z;
    }

    // skew realign + combine + causal mask
    bool needMask = (t0 + wc * 64 + 63 > sw);
    #pragma unroll
    for (int r = 0; r < 4; ++r) {
      int srow = g * 4 + r;
      int dsh = 15 - srow + l15;                 // 0..30
      int srcl = (lane & 48) + (dsh & 15);
      float sh[5];
      #pragma unroll
      for (int nb = 0; nb < 5; ++nb) sh[nb] = __shfl(accR[nb][r], srcl);
      bool cy = dsh >= 16;
      #pragma unroll
      for (int ni = 0; ni < 4; ++ni) {
        float rel = cy ? sh[ni + 1] : sh[ni];
        float val = accS[ni][r] + rel;
        if (needMask && (t0 + wc * 64 + ni * 16 + l15 > sw + srow)) val = -1e30f;
        accS[ni][r] = val;
      }
    }

    // local row max -> exchange across column halves
    float lmax[4];
    #pragma unroll
    for (int r = 0; r < 4; ++r) {
      float tm = fmaxf(fmaxf(accS[0][r], accS[1][r]), fmaxf(accS[2][r], accS[3][r]));
      tm = fmaxf(tm, __shfl_xor(tm, 1));
      tm = fmaxf(tm, __shfl_xor(tm, 2));
      tm = fmaxf(tm, __shfl_xor(tm, 4));
      tm = fmaxf(tm, __shfl_xor(tm, 8));
      lmax[r] = tm;
    }
    if (l15 == 0) {
      #pragma unroll
      for (int r = 0; r < 4; ++r) sM[wc][wr * 16 + g * 4 + r] = lmax[r];
    }
    __syncthreads();                              // B1
    float4 om = *(float4*)&sM[wc ^ 1][wr * 16 + g * 4];

    // global max -> rescale o, exp, local sums
    float sesav[4], lscl[4];
    #pragma unroll
    for (int r = 0; r < 4; ++r) {
      float gm = fmaxf(lmax[r], ((float*)&om)[r]);
      float mnew = fmaxf(mrow[r], gm);
      lscl[r] = exp2f(mrow[r] - mnew);
      mrow[r] = mnew;
      float se = 0.f;
      #pragma unroll
      for (int ni = 0; ni < 4; ++ni) {
        float pe = exp2f(accS[ni][r] - mnew);
        accS[ni][r] = pe;
        se += pe;
      }
      se += __shfl_xor(se, 1); se += __shfl_xor(se, 2);
      se += __shfl_xor(se, 4); se += __shfl_xor(se, 8);
      sesav[r] = se;
      o[0][r] *= lscl[r]; o[1][r] *= lscl[r]; o[2][r] *= lscl[r]; o[3][r] *= lscl[r];
    }
    if (l15 == 0) {
      #pragma unroll
      for (int r = 0; r < 4; ++r) sS[wc][wr * 16 + g * 4 + r] = sesav[r];
    }

    // P -> per-wave LDS, then PV (accumulates into rescaled o)
    #pragma unroll
    for (int ni = 0; ni < 4; ++ni)
      #pragma unroll
      for (int r = 0; r < 4; ++r) {
        int srow = g * 4 + r;
        int chunk = (ni * 2 + (l15 >> 3)) ^ (srow & 7);
        sP[wv][srow * 64 + chunk * 8 + (l15 & 7)] = f2bf(accS[ni][r]);
      }
    asm volatile("s_waitcnt lgkmcnt(0)" ::: "memory");
    __builtin_amdgcn_sched_barrier(0);
    #pragma unroll
    for (int kk = 0; kk < 2; ++kk) {
      short8 pf = *(const short8*)&sP[wv][l15 * 64 + (((kk * 4 + g) ^ (l15 & 7)) * 8)];
      #pragma unroll
      for (int nb = 0; nb < 4; ++nb) {
        int d = nb * 16 + l15;
        int ck = wc * 8 + kk * 4 + g;
        short8 vf = *(const short8*)&sV[d * (KVB + 8) + ((ck ^ (d >> 3)) * 8)];
        o[nb] = __builtin_amdgcn_mfma_f32_16x16x32_bf16(pf, vf, o[nb], 0, 0, 0);
      }
    }

    __syncthreads();                              // B2 (drains vm+lgkm)
    float4 os = *(float4*)&sS[wc ^ 1][wr * 16 + g * 4];
    #pragma unroll
    for (int r = 0; r < 4; ++r)
      lsum[r] = lsum[r] * lscl[r] + sesav[r] + ((float*)&os)[r];

    // write prefetched V^T into sV (reads of this iter are done; next
    // iteration's B1 orders these writes before its PV reads)
    if (pre) {
      #pragma unroll
      for (int q = 0; q < 4; ++q) {
        int t = q * 32 + rstage;
        #pragma unroll
        for (int j = 0; j < 8; ++j) {
          int d = cstage + j;
          sV[d * (KVB + 8) + (((t >> 3) ^ (d >> 3)) * 8) + (t & 7)] = (u16)vp[q][j];
        }
      }
    }
  }

  flushOut(tileB);
}

// ---------------------------------------------------------------------------
extern "C" void kernel_launch(void* const* d_in, const int* in_sizes, int n_in,
                              void* d_out, int out_size, void* d_ws, size_t ws_size,
                              hipStream_t stream) {
  const float* x     = (const float*)d_in[0];
  // d_in[1] = mask: recomputed causally in-kernel
  const float* Wqkv  = (const float*)d_in[2];
  const float* bqkv  = (const float*)d_in[3];
  const float* Wproj = (const float*)d_in[4];
  const float* bproj = (const float*)d_in[5];
  const float* E     = (const float*)d_in[6];
  const float* g1    = (const float*)d_in[7];
  const float* b1    = (const float*)d_in[8];
  const float* g2    = (const float*)d_in[9];
  const float* b2    = (const float*)d_in[10];
  const float* W1    = (const float*)d_in[11];
  const float* bm1   = (const float*)d_in[12];
  const float* W2    = (const float*)d_in[13];
  const float* bm2   = (const float*)d_in[14];
  float* out = (float*)d_out;

  char* ws = (char*)d_ws;
  size_t off = 0;
  auto alloc = [&](size_t bytes) {
    void* p = ws + off;
    off += (bytes + 255) & ~(size_t)255;
    return p;
  };
  u16* a_bf   = (u16*)alloc((size_t)NROWS * DM * 2);      // LN1 out, reused for LN2 out
  u16* q_bf   = (u16*)alloc((size_t)NROWS * DM * 2);
  u16* k_bf   = (u16*)alloc((size_t)NROWS * DM * 2);
  u16* v_bf   = (u16*)alloc((size_t)NROWS * DM * 2);
  u16* att_bf = (u16*)alloc((size_t)NROWS * DM * 2);
  float* y    = (float*)alloc((size_t)NROWS * DM * 4);
  u16* h_bf   = (u16*)alloc((size_t)NROWS * 2048 * 2);
  u16* WqkvT  = (u16*)alloc((size_t)1536 * 512 * 2);
  u16* WprojT = (u16*)alloc((size_t)512 * 512 * 2);
  u16* W1T    = (u16*)alloc((size_t)2048 * 512 * 2);
  u16* W2T    = (u16*)alloc((size_t)512 * 2048 * 2);
  u16* E_bf   = (u16*)alloc((size_t)NH * SEQ * DH * 2);

  // weights -> bf16 (transposed to N x K)
  transpose_cast_kernel<<<dim3(1536 / 32, 512 / 32), 256, 0, stream>>>(Wqkv, WqkvT, 512, 1536);
  transpose_cast_kernel<<<dim3(512 / 32, 512 / 32), 256, 0, stream>>>(Wproj, WprojT, 512, 512);
  transpose_cast_kernel<<<dim3(2048 / 32, 512 / 32), 256, 0, stream>>>(W1, W1T, 512, 2048);
  transpose_cast_kernel<<<dim3(512 / 32, 2048 / 32), 256, 0, stream>>>(W2, W2T, 2048, 512);
  cast_bf16_kernel<<<(NH * SEQ * DH) / (256 * 4), 256, 0, stream>>>(E, E_bf, NH * SEQ * DH);

  // LN1
  ln_bf16_kernel<<<NROWS, 64, 0, stream>>>(x, g1, b1, a_bf);
  // QKV (q pre-scaled by 0.125*log2e); grid 768 = 64x12 (3/CU)
  gemm_bf16<64, 128, 0><<<(NROWS / 64) * (1536 / 128), 256, 0, stream>>>(
      a_bf, WqkvT, bqkv, nullptr, nullptr, q_bf, k_bf, v_bf, NROWS, 1536, 512);
  // attention (R4 structure: balanced fold, 512 blocks)
  attn_kernel<<<512, 256, 0, stream>>>(q_bf, k_bf, v_bf, E_bf, att_bf);
  // proj + residual -> y (fp32); grid 512 = 64x8
  gemm_bf16<64, 64, 1><<<(NROWS / 64) * (512 / 64), 256, 0, stream>>>(
      att_bf, WprojT, bproj, x, y, nullptr, nullptr, nullptr, NROWS, 512, 512);
  // LN2 (reuse a_bf as m_bf)
  ln_bf16_kernel<<<NROWS, 64, 0, stream>>>(y, g2, b2, a_bf);
  // FFN1 + gelu; grid 1024 = 64x16 (4/CU)
  gemm_bf16<64, 128, 2><<<(NROWS / 64) * (2048 / 128), 256, 0, stream>>>(
      a_bf, W1T, bm1, nullptr, nullptr, h_bf, nullptr, nullptr, NROWS, 2048, 512);
  // FFN2 + residual -> out; grid 512 = 64x8, 32 K-steps
  gemm_bf16<64, 64, 3><<<(NROWS / 64) * (512 / 64), 256, 0, stream>>>(
      h_bf, W2T, bm2, y, out, nullptr, nullptr, nullptr, NROWS, 512, 2048);
}

// Round 9
// 170.967 us; speedup vs baseline: 1.4649x; 1.0045x over previous
//
#include <hip/hip_runtime.h>
#include <math.h>

typedef unsigned short u16;
typedef unsigned int u32;
using short8 = __attribute__((ext_vector_type(8))) short;
using f32x4  = __attribute__((ext_vector_type(4))) float;

#define SEQ 2048
#define NH 8
#define DM 512
#define DH 64
#define NROWS 4096  // B*S
#define BATCH 2
#define KVB 128

__device__ __forceinline__ float bf2f(u16 u) {
  union { u32 i; float f; } c; c.i = ((u32)u) << 16; return c.f;
}
__device__ __forceinline__ u16 f2bf(float f) {
  union { float f; u32 i; } c; c.f = f;
  u32 r = c.i + 0x7fffu + ((c.i >> 16) & 1u);
  return (u16)(r >> 16);
}

// async global->LDS, 16B per lane. LDS dest must be wave-uniform base.
__device__ __forceinline__ void gll16(const u16* g, u16* l) {
  __builtin_amdgcn_global_load_lds(
      (const __attribute__((address_space(1))) u32*)g,
      (__attribute__((address_space(3))) u32*)l, 16, 0, 0);
}

template<int N> __device__ __forceinline__ void waitcnt_vm() {
  if constexpr (N == 0)      asm volatile("s_waitcnt vmcnt(0)" ::: "memory");
  else if constexpr (N == 4) asm volatile("s_waitcnt vmcnt(4)" ::: "memory");
  else if constexpr (N == 6) asm volatile("s_waitcnt vmcnt(6)" ::: "memory");
  else if constexpr (N == 8) asm volatile("s_waitcnt vmcnt(8)" ::: "memory");
}

// ---------------- LayerNorm (fp32 in -> bf16 out), one wave per 512-row ----
__global__ __launch_bounds__(64) void ln_bf16_kernel(
    const float* __restrict__ x, const float* __restrict__ gw,
    const float* __restrict__ bw, u16* __restrict__ out)
{
  int row = blockIdx.x;
  int lane = threadIdx.x;
  const float* xr = x + (size_t)row * DM;
  float4 v0 = ((const float4*)xr)[lane];
  float4 v1 = ((const float4*)xr)[lane + 64];
  float s  = v0.x + v0.y + v0.z + v0.w + v1.x + v1.y + v1.z + v1.w;
  float s2 = v0.x*v0.x + v0.y*v0.y + v0.z*v0.z + v0.w*v0.w
           + v1.x*v1.x + v1.y*v1.y + v1.z*v1.z + v1.w*v1.w;
  #pragma unroll
  for (int m = 1; m < 64; m <<= 1) {
    s  += __shfl_xor(s,  m);
    s2 += __shfl_xor(s2, m);
  }
  float mu   = s * (1.0f / DM);
  float var  = s2 * (1.0f / DM) - mu * mu;
  float rstd = rsqrtf(var + 1e-5f);
  float4 ga = ((const float4*)gw)[lane],      ba = ((const float4*)bw)[lane];
  float4 gb = ((const float4*)gw)[lane + 64], bb = ((const float4*)bw)[lane + 64];
  ushort4 o0, o1;
  o0.x = f2bf((v0.x - mu) * rstd * ga.x + ba.x);
  o0.y = f2bf((v0.y - mu) * rstd * ga.y + ba.y);
  o0.z = f2bf((v0.z - mu) * rstd * ga.z + ba.z);
  o0.w = f2bf((v0.w - mu) * rstd * ga.w + ba.w);
  o1.x = f2bf((v1.x - mu) * rstd * gb.x + bb.x);
  o1.y = f2bf((v1.y - mu) * rstd * gb.y + bb.y);
  o1.z = f2bf((v1.z - mu) * rstd * gb.z + bb.z);
  o1.w = f2bf((v1.w - mu) * rstd * gb.w + bb.w);
  *(ushort4*)&out[(size_t)row * DM + lane * 4]       = o0;
  *(ushort4*)&out[(size_t)row * DM + 256 + lane * 4] = o1;
}

// ---------------- Transpose + cast fp32 (K x N) -> bf16 (N x K) ------------
__global__ __launch_bounds__(256) void transpose_cast_kernel(
    const float* __restrict__ W, u16* __restrict__ Wt, int K, int N)
{
  __shared__ float tile[32][33];
  int bn = blockIdx.x * 32, bk = blockIdx.y * 32;
  int tx = threadIdx.x & 31, ty = threadIdx.x >> 5; // 32 x 8
  #pragma unroll
  for (int i = 0; i < 32; i += 8)
    tile[ty + i][tx] = W[(size_t)(bk + ty + i) * N + bn + tx];
  __syncthreads();
  #pragma unroll
  for (int i = 0; i < 32; i += 8)
    Wt[(size_t)(bn + ty + i) * K + bk + tx] = f2bf(tile[tx][ty + i]);
}

// ---------------- Elementwise cast fp32 -> bf16 ----------------------------
__global__ __launch_bounds__(256) void cast_bf16_kernel(
    const float* __restrict__ in, u16* __restrict__ out, int n)
{
  int i = (blockIdx.x * 256 + threadIdx.x) * 4;
  if (i >= n) return;
  float4 v = *(const float4*)&in[i];
  ushort4 o;
  o.x = f2bf(v.x); o.y = f2bf(v.y); o.z = f2bf(v.z); o.w = f2bf(v.w);
  *(ushort4*)&out[i] = o;
}

// ---------------- TMxTN MFMA GEMM, BK=64, counted-vmcnt 2-phase pipeline ---
// 1-D grid (nwg % 8 == 0), bijective XCD swizzle. Per K-step:
// barrier -> stage(next buf) -> vmcnt(LOADS) [waits PREVIOUS stage only]
// -> barrier -> MFMA(cur buf). Never drains the in-flight prefetch.
template<int TM, int TN, int MODE>
__global__ __launch_bounds__(256) void gemm_bf16(
    const u16* __restrict__ A, const u16* __restrict__ Bt,
    const float* __restrict__ bias, const float* __restrict__ res,
    float* __restrict__ outF, u16* __restrict__ outB0,
    u16* __restrict__ outB1, u16* __restrict__ outB2,
    int M, int N, int K)
{
  constexpr int MI = TM / 32;       // m-frags per wave
  constexpr int NI = TN / 32;       // n-frags per wave
  constexpr int LOADS = TM / 32 + TN / 32;  // gll16 per thread per stage
  __shared__ u16 sA[2][TM * 64];
  __shared__ u16 sB[2][TN * 64];
  int tid = threadIdx.x;
  int lane = tid & 63, wv = tid >> 6;
  int wm = wv >> 1, wn = wv & 1;
  int g = lane >> 4, l15 = lane & 15;

  int nwg = gridDim.x, lin = blockIdx.x;
  int qq = nwg >> 3;
  int wg = (lin & 7) * qq + (lin >> 3);     // bijective: nwg % 8 == 0
  int ntn = N / TN;
  int m0 = (wg / ntn) * TM, n0 = (wg % ntn) * TN;

  auto stage = [&](int buf, int k0) {
    #pragma unroll
    for (int s = 0; s < TM / 32; ++s) {     // A: TM rows x 8 chunks
      int c = s * 256 + tid;
      int row = c >> 3, p = c & 7;
      gll16(&A[(size_t)(m0 + row) * K + k0 + ((p ^ (row & 7)) * 8)],
            &sA[buf][(size_t)(s * 256 + wv * 64) * 8]);
    }
    #pragma unroll
    for (int s = 0; s < TN / 32; ++s) {     // B: TN rows x 8 chunks
      int c = s * 256 + tid;
      int row = c >> 3, p = c & 7;
      gll16(&Bt[(size_t)(n0 + row) * K + k0 + ((p ^ (row & 7)) * 8)],
            &sB[buf][(size_t)(s * 256 + wv * 64) * 8]);
    }
  };

  f32x4 acc[MI][NI] = {};
  stage(0, 0);

  int nk = K / 64;
  for (int kt = 0; kt < nk; ++kt) {
    int cur = kt & 1;
    __syncthreads();                         // buf cur^1 reads (prev compute) done
    if (kt + 1 < nk) {
      stage(cur ^ 1, (kt + 1) * 64);         // prefetch into freed buffer
      waitcnt_vm<LOADS>();                   // wait only for PREVIOUS stage
    } else {
      waitcnt_vm<0>();
    }
    __syncthreads();                         // buf cur visible to all waves
    #pragma unroll
    for (int kk = 0; kk < 2; ++kk) {
      short8 af[MI], bfr[NI];
      #pragma unroll
      for (int i = 0; i < MI; ++i) {
        int row = wm * (TM / 2) + i * 16 + l15;
        af[i] = *(const short8*)&sA[cur][row * 64 + (((4 * kk + g) ^ (row & 7)) * 8)];
      }
      #pragma unroll
      for (int i = 0; i < NI; ++i) {
        int row = wn * (TN / 2) + i * 16 + l15;
        bfr[i] = *(const short8*)&sB[cur][row * 64 + (((4 * kk + g) ^ (row & 7)) * 8)];
      }
      #pragma unroll
      for (int mi = 0; mi < MI; ++mi)
        #pragma unroll
        for (int ni = 0; ni < NI; ++ni)
          acc[mi][ni] = __builtin_amdgcn_mfma_f32_16x16x32_bf16(af[mi], bfr[ni], acc[mi][ni], 0, 0, 0);
    }
  }

  #pragma unroll
  for (int mi = 0; mi < MI; ++mi) {
    #pragma unroll
    for (int ni = 0; ni < NI; ++ni) {
      #pragma unroll
      for (int r = 0; r < 4; ++r) {
        int grow = m0 + wm * (TM / 2) + mi * 16 + g * 4 + r;
        int gcol = n0 + wn * (TN / 2) + ni * 16 + l15;
        float val = acc[mi][ni][r] + bias[gcol];
        if (MODE == 0) {
          int part = gcol >> 9, c = gcol & 511;
          int hh = c >> 6, dd = c & 63;
          int bb = grow >> 11, ss = grow & 2047;
          size_t dst = (((size_t)(bb * NH + hh)) * SEQ + ss) * DH + dd;
          if (part == 0)      outB0[dst] = f2bf(val * 0.18033688011112042f); // q * 0.125*log2(e)
          else if (part == 1) outB1[dst] = f2bf(val);           // k
          else                outB2[dst] = f2bf(val);           // v
        } else if (MODE == 1 || MODE == 3) {
          size_t idx = (size_t)grow * DM + gcol;
          outF[idx] = val + res[idx];
        } else { // MODE 2: gelu (tanh approx = jax.nn.gelu default)
          float t = val;
          float inner = 0.7978845608028654f * (t + 0.044715f * t * t * t);
          float gl = 0.5f * t * (1.0f + tanhf(inner));
          outB0[(size_t)grow * N + gcol] = f2bf(gl);
        }
      }
    }
  }
}

// ---------------- Flash causal attention with relative positions -----------
// R4 decomposition (best measured), single-buffered K for occupancy:
// 512 blocks, LDS ~42.5KB -> 3 blocks/CU (12 waves/CU). All sK reads finish
// before B1, so next K tile's global_load_lds is issued right after B1 into
// the SAME buffer; B2's vmcnt(0) drains it before next iteration's reads.
__global__ __launch_bounds__(256, 2) void attn_kernel(
    const u16* __restrict__ Q, const u16* __restrict__ Kb,
    const u16* __restrict__ Vb, const u16* __restrict__ Eb,
    u16* __restrict__ Ob)
{
  __shared__ u16 sK[KVB * 64];           // 16KB, chunk-swizzled linear (gll)
  __shared__ u16 sV[64 * (KVB + 8)];     // 17.4KB, [d][t] block-XOR, single
  __shared__ u16 sP[4][16 * 64];         // 8KB, per-wave (sO overlays)
  __shared__ float sM[2][32];            // cross-half max exchange
  __shared__ float sS[2][32];            // cross-half sum exchange

  int tid = threadIdx.x, lane = tid & 63, wv = tid >> 6;
  int wr = wv & 1, wc = wv >> 1;
  int g = lane >> 4, l15 = lane & 15;
  int blk = blockIdx.x;
  int bh = blk >> 5, pp = blk & 31;
  int hh = bh & (NH - 1), bb = bh >> 3;

  const u16* Qh = Q  + (size_t)bh * SEQ * DH;
  const u16* Kh = Kb + (size_t)bh * SEQ * DH;
  const u16* Vh = Vb + (size_t)bh * SEQ * DH;
  const u16* Eh = Eb + (size_t)hh * SEQ * DH;

  int tileA = pp, tileB = 63 - pp;
  int itersA = pp / 4 + 1;
  const int TOT = 17;

  int rstage = tid >> 3, cstage = (tid & 7) * 8;

  // ---- prologue: stage kt=0 ----
  #pragma unroll
  for (int s = 0; s < 4; ++s) {
    int c = s * 256 + tid, t = c >> 3, pc = c & 7;
    gll16(&Kh[(size_t)t * DH + ((pc ^ (t & 7)) * 8)],
          &sK[(size_t)(s * 256 + wv * 64) * 8]);
  }
  #pragma unroll
  for (int q = 0; q < 4; ++q) {
    int t = q * 32 + rstage;
    short8 vv = *(const short8*)&Vh[(size_t)t * DH + cstage];
    #pragma unroll
    for (int j = 0; j < 8; ++j) {
      int d = cstage + j;
      sV[d * (KVB + 8) + (((t >> 3) ^ (d >> 3)) * 8) + (t & 7)] = (u16)vv[j];
    }
  }
  asm volatile("s_waitcnt vmcnt(0)" ::: "memory");
  __syncthreads();

  short8 qf[2];
  {
    int sw = tileA * 32 + wr * 16;
    qf[0] = *(const short8*)&Qh[(size_t)(sw + l15) * DH + g * 8];
    qf[1] = *(const short8*)&Qh[(size_t)(sw + l15) * DH + g * 8 + 32];
  }
  f32x4 o[4] = {};
  float mrow[4] = {-1e30f, -1e30f, -1e30f, -1e30f};
  float lsum[4] = {};

  float* sO = (float*)&sP[0][0];   // [2][16][64] f32 overlay at flush time

  auto flushOut = [&](int tile) {
    int swt = tile * 32 + wr * 16;
    if (wc == 1) {
      #pragma unroll
      for (int r = 0; r < 4; ++r) {
        float rl = 1.0f / lsum[r];
        #pragma unroll
        for (int nb = 0; nb < 4; ++nb)
          sO[wr * 1024 + (g * 4 + r) * 64 + nb * 16 + l15] = o[nb][r] * rl;
      }
    }
    __syncthreads();
    if (wc == 0) {
      #pragma unroll
      for (int r = 0; r < 4; ++r) {
        float rl = 1.0f / lsum[r];
        int ss = swt + g * 4 + r;
        #pragma unroll
        for (int nb = 0; nb < 4; ++nb) {
          float val = o[nb][r] * rl + sO[wr * 1024 + (g * 4 + r) * 64 + nb * 16 + l15];
          Ob[((size_t)(bb * SEQ + ss)) * DM + hh * DH + nb * 16 + l15] = f2bf(val);
        }
      }
    }
  };

  for (int it = 0; it < TOT; ++it) {
    if (it == itersA) {
      flushOut(tileA);
      #pragma unroll
      for (int nb = 0; nb < 4; ++nb) o[nb] = f32x4{};
      #pragma unroll
      for (int r = 0; r < 4; ++r) { mrow[r] = -1e30f; lsum[r] = 0.f; }
      int sw = tileB * 32 + wr * 16;
      qf[0] = *(const short8*)&Qh[(size_t)(sw + l15) * DH + g * 8];
      qf[1] = *(const short8*)&Qh[(size_t)(sw + l15) * DH + g * 8 + 32];
    }
    int tile = (it < itersA) ? tileA : tileB;
    int kt   = (it < itersA) ? it : it - itersA;
    int sw = tile * 32 + wr * 16, t0 = kt * KVB;

    // prefetch next V into regs (issue at top: longest latency window)
    bool pre = (it + 1 < TOT);
    int tb = 0;
    short8 vp[4];
    if (pre) {
      int kn = (it + 1 < itersA) ? it + 1 : it + 1 - itersA;
      tb = kn * KVB;
      #pragma unroll
      for (int q = 0; q < 4; ++q)
        vp[q] = *(const short8*)&Vh[(size_t)(tb + q * 32 + rstage) * DH + cstage];
    }

    // S1 = Q K^T (16 rows x 64 cols per wave, this wave's column half)
    f32x4 accS[4];
    #pragma unroll
    for (int ni = 0; ni < 4; ++ni) {
      int row = wc * 64 + ni * 16 + l15;
      short8 k0 = *(const short8*)&sK[row * 64 + ((g ^ (row & 7)) * 8)];
      short8 k1 = *(const short8*)&sK[row * 64 + (((4 + g) ^ (row & 7)) * 8)];
      f32x4 z = {};
      z = __builtin_amdgcn_mfma_f32_16x16x32_bf16(qf[0], k0, z, 0, 0, 0);
      z = __builtin_amdgcn_mfma_f32_16x16x32_bf16(qf[1], k1, z, 0, 0, 0);
      accS[ni] = z;
    }

    // S2 = Q E^T strip (16 x 80): rel[s,t] = q[s].E[2047 - s + t]
    int jbase = 2032 - sw + t0 + wc * 64;
    f32x4 accR[5];
    #pragma unroll
    for (int nb = 0; nb < 5; ++nb) {
      int j = jbase + nb * 16 + l15; if (j > 2047) j = 2047;
      short8 e0 = *(const short8*)&Eh[(size_t)j * DH + g * 8];
      short8 e1 = *(const short8*)&Eh[(size_t)j * DH + 32 + g * 8];
      f32x4 z = {};
      z = __builtin_amdgcn_mfma_f32_16x16x32_bf16(qf[0], e0, z, 0, 0, 0);
      z = __builtin_amdgcn_mfma_f32_16x16x32_bf16(qf[1], e1, z, 0, 0, 0);
      accR[nb] = z;
    }

    // skew realign + combine + causal mask
    bool needMask = (t0 + wc * 64 + 63 > sw);
    #pragma unroll
    for (int r = 0; r < 4; ++r) {
      int srow = g * 4 + r;
      int dsh = 15 - srow + l15;                 // 0..30
      int srcl = (lane & 48) + (dsh & 15);
      float sh[5];
      #pragma unroll
      for (int nb = 0; nb < 5; ++nb) sh[nb] = __shfl(accR[nb][r], srcl);
      bool cy = dsh >= 16;
      #pragma unroll
      for (int ni = 0; ni < 4; ++ni) {
        float rel = cy ? sh[ni + 1] : sh[ni];
        float val = accS[ni][r] + rel;
        if (needMask && (t0 + wc * 64 + ni * 16 + l15 > sw + srow)) val = -1e30f;
        accS[ni][r] = val;
      }
    }

    // local row max -> exchange across column halves
    float lmax[4];
    #pragma unroll
    for (int r = 0; r < 4; ++r) {
      float tm = fmaxf(fmaxf(accS[0][r], accS[1][r]), fmaxf(accS[2][r], accS[3][r]));
      tm = fmaxf(tm, __shfl_xor(tm, 1));
      tm = fmaxf(tm, __shfl_xor(tm, 2));
      tm = fmaxf(tm, __shfl_xor(tm, 4));
      tm = fmaxf(tm, __shfl_xor(tm, 8));
      lmax[r] = tm;
    }
    if (l15 == 0) {
      #pragma unroll
      for (int r = 0; r < 4; ++r) sM[wc][wr * 16 + g * 4 + r] = lmax[r];
    }
    __syncthreads();                              // B1: all sK reads done
    // issue next K tile into the SAME sK buffer (drained at B2)
    if (pre) {
      #pragma unroll
      for (int s = 0; s < 4; ++s) {
        int c = s * 256 + tid, t = c >> 3, pc = c & 7;
        gll16(&Kh[(size_t)(tb + t) * DH + ((pc ^ (t & 7)) * 8)],
              &sK[(size_t)(s * 256 + wv * 64) * 8]);
      }
    }
    float4 om = *(float4*)&sM[wc ^ 1][wr * 16 + g * 4];

    // global max -> rescale o, exp, local sums
    float sesav[4], lscl[4];
    #pragma unroll
    for (int r = 0; r < 4; ++r) {
      float gm = fmaxf(lmax[r], ((float*)&om)[r]);
      float mnew = fmaxf(mrow[r], gm);
      lscl[r] = exp2f(mrow[r] - mnew);
      mrow[r] = mnew;
      float se = 0.f;
      #pragma unroll
      for (int ni = 0; ni < 4; ++ni) {
        float pe = exp2f(accS[ni][r] - mnew);
        accS[ni][r] = pe;
        se += pe;
      }
      se += __shfl_xor(se, 1); se += __shfl_xor(se, 2);
      se += __shfl_xor(se, 4); se += __shfl_xor(se, 8);
      sesav[r] = se;
      o[0][r] *= lscl[r]; o[1][r] *= lscl[r]; o[2][r] *= lscl[r]; o[3][r] *= lscl[r];
    }
    if (l15 == 0) {
      #pragma unroll
      for (int r = 0; r < 4; ++r) sS[wc][wr * 16 + g * 4 + r] = sesav[r];
    }

    // P -> per-wave LDS, then PV (accumulates into rescaled o)
    #pragma unroll
    for (int ni = 0; ni < 4; ++ni)
      #pragma unroll
      for (int r = 0; r < 4; ++r) {
        int srow = g * 4 + r;
        int chunk = (ni * 2 + (l15 >> 3)) ^ (srow & 7);
        sP[wv][srow * 64 + chunk * 8 + (l15 & 7)] = f2bf(accS[ni][r]);
      }
    asm volatile("s_waitcnt lgkmcnt(0)" ::: "memory");
    __builtin_amdgcn_sched_barrier(0);
    #pragma unroll
    for (int kk = 0; kk < 2; ++kk) {
      short8 pf = *(const short8*)&sP[wv][l15 * 64 + (((kk * 4 + g) ^ (l15 & 7)) * 8)];
      #pragma unroll
      for (int nb = 0; nb < 4; ++nb) {
        int d = nb * 16 + l15;
        int ck = wc * 8 + kk * 4 + g;
        short8 vf = *(const short8*)&sV[d * (KVB + 8) + ((ck ^ (d >> 3)) * 8)];
        o[nb] = __builtin_amdgcn_mfma_f32_16x16x32_bf16(pf, vf, o[nb], 0, 0, 0);
      }
    }

    __syncthreads();                              // B2 (drains vm+lgkm: K staged)
    float4 os = *(float4*)&sS[wc ^ 1][wr * 16 + g * 4];
    #pragma unroll
    for (int r = 0; r < 4; ++r)
      lsum[r] = lsum[r] * lscl[r] + sesav[r] + ((float*)&os)[r];

    // write prefetched V^T into sV (reads of this iter are done; next
    // iteration's B1 orders these writes before its PV reads)
    if (pre) {
      #pragma unroll
      for (int q = 0; q < 4; ++q) {
        int t = q * 32 + rstage;
        #pragma unroll
        for (int j = 0; j < 8; ++j) {
          int d = cstage + j;
          sV[d * (KVB + 8) + (((t >> 3) ^ (d >> 3)) * 8) + (t & 7)] = (u16)vp[q][j];
        }
      }
    }
  }

  flushOut(tileB);
}

// ---------------------------------------------------------------------------
extern "C" void kernel_launch(void* const* d_in, const int* in_sizes, int n_in,
                              void* d_out, int out_size, void* d_ws, size_t ws_size,
                              hipStream_t stream) {
  const float* x     = (const float*)d_in[0];
  // d_in[1] = mask: recomputed causally in-kernel
  const float* Wqkv  = (const float*)d_in[2];
  const float* bqkv  = (const float*)d_in[3];
  const float* Wproj = (const float*)d_in[4];
  const float* bproj = (const float*)d_in[5];
  const float* E     = (const float*)d_in[6];
  const float* g1    = (const float*)d_in[7];
  const float* b1    = (const float*)d_in[8];
  const float* g2    = (const float*)d_in[9];
  const float* b2    = (const float*)d_in[10];
  const float* W1    = (const float*)d_in[11];
  const float* bm1   = (const float*)d_in[12];
  const float* W2    = (const float*)d_in[13];
  const float* bm2   = (const float*)d_in[14];
  float* out = (float*)d_out;

  char* ws = (char*)d_ws;
  size_t off = 0;
  auto alloc = [&](size_t bytes) {
    void* p = ws + off;
    off += (bytes + 255) & ~(size_t)255;
    return p;
  };
  u16* a_bf   = (u16*)alloc((size_t)NROWS * DM * 2);      // LN1 out, reused for LN2 out
  u16* q_bf   = (u16*)alloc((size_t)NROWS * DM * 2);
  u16* k_bf   = (u16*)alloc((size_t)NROWS * DM * 2);
  u16* v_bf   = (u16*)alloc((size_t)NROWS * DM * 2);
  u16* att_bf = (u16*)alloc((size_t)NROWS * DM * 2);
  float* y    = (float*)alloc((size_t)NROWS * DM * 4);
  u16* h_bf   = (u16*)alloc((size_t)NROWS * 2048 * 2);
  u16* WqkvT  = (u16*)alloc((size_t)1536 * 512 * 2);
  u16* WprojT = (u16*)alloc((size_t)512 * 512 * 2);
  u16* W1T    = (u16*)alloc((size_t)2048 * 512 * 2);
  u16* W2T    = (u16*)alloc((size_t)512 * 2048 * 2);
  u16* E_bf   = (u16*)alloc((size_t)NH * SEQ * DH * 2);

  // weights -> bf16 (transposed to N x K)
  transpose_cast_kernel<<<dim3(1536 / 32, 512 / 32), 256, 0, stream>>>(Wqkv, WqkvT, 512, 1536);
  transpose_cast_kernel<<<dim3(512 / 32, 512 / 32), 256, 0, stream>>>(Wproj, WprojT, 512, 512);
  transpose_cast_kernel<<<dim3(2048 / 32, 512 / 32), 256, 0, stream>>>(W1, W1T, 512, 2048);
  transpose_cast_kernel<<<dim3(512 / 32, 2048 / 32), 256, 0, stream>>>(W2, W2T, 2048, 512);
  cast_bf16_kernel<<<(NH * SEQ * DH) / (256 * 4), 256, 0, stream>>>(E, E_bf, NH * SEQ * DH);

  // LN1
  ln_bf16_kernel<<<NROWS, 64, 0, stream>>>(x, g1, b1, a_bf);
  // QKV (q pre-scaled by 0.125*log2e); grid 768 = 64x12 (3/CU)
  gemm_bf16<64, 128, 0><<<(NROWS / 64) * (1536 / 128), 256, 0, stream>>>(
      a_bf, WqkvT, bqkv, nullptr, nullptr, q_bf, k_bf, v_bf, NROWS, 1536, 512);
  // attention (R4 decomposition, single-buffered K, 3 blocks/CU)
  attn_kernel<<<512, 256, 0, stream>>>(q_bf, k_bf, v_bf, E_bf, att_bf);
  // proj + residual -> y (fp32); grid 512 = 64x8
  gemm_bf16<64, 64, 1><<<(NROWS / 64) * (512 / 64), 256, 0, stream>>>(
      att_bf, WprojT, bproj, x, y, nullptr, nullptr, nullptr, NROWS, 512, 512);
  // LN2 (reuse a_bf as m_bf)
  ln_bf16_kernel<<<NROWS, 64, 0, stream>>>(y, g2, b2, a_bf);
  // FFN1 + gelu; grid 1024 = 64x16 (4/CU)
  gemm_bf16<64, 128, 2><<<(NROWS / 64) * (2048 / 128), 256, 0, stream>>>(
      a_bf, W1T, bm1, nullptr, nullptr, h_bf, nullptr, nullptr, NROWS, 2048, 512);
  // FFN2 + residual -> out; grid 512 = 64x8, 32 K-steps
  gemm_bf16<64, 64, 3><<<(NROWS / 64) * (512 / 64), 256, 0, stream>>>(
      h_bf, W2T, bm2, y, out, nullptr, nullptr, nullptr, NROWS, 512, 2048);
}

// Round 10
// 168.710 us; speedup vs baseline: 1.4845x; 1.0134x over previous
//
#include <hip/hip_runtime.h>
#include <math.h>

typedef unsigned short u16;
typedef unsigned int u32;
using short8 = __attribute__((ext_vector_type(8))) short;
using f32x4  = __attribute__((ext_vector_type(4))) float;

#define SEQ 2048
#define NH 8
#define DM 512
#define DH 64
#define NROWS 4096  // B*S
#define BATCH 2
#define KVB 128

__device__ __forceinline__ float bf2f(u16 u) {
  union { u32 i; float f; } c; c.i = ((u32)u) << 16; return c.f;
}
__device__ __forceinline__ u16 f2bf(float f) {
  union { float f; u32 i; } c; c.f = f;
  u32 r = c.i + 0x7fffu + ((c.i >> 16) & 1u);
  return (u16)(r >> 16);
}

// async global->LDS, 16B per lane. LDS dest must be wave-uniform base.
__device__ __forceinline__ void gll16(const u16* g, u16* l) {
  __builtin_amdgcn_global_load_lds(
      (const __attribute__((address_space(1))) u32*)g,
      (__attribute__((address_space(3))) u32*)l, 16, 0, 0);
}

template<int N> __device__ __forceinline__ void waitcnt_vm() {
  if constexpr (N == 0)      asm volatile("s_waitcnt vmcnt(0)" ::: "memory");
  else if constexpr (N == 4) asm volatile("s_waitcnt vmcnt(4)" ::: "memory");
  else if constexpr (N == 6) asm volatile("s_waitcnt vmcnt(6)" ::: "memory");
  else if constexpr (N == 8) asm volatile("s_waitcnt vmcnt(8)" ::: "memory");
}

// ---------------- LayerNorm (fp32 in -> bf16 out), one wave per 512-row ----
__global__ __launch_bounds__(64) void ln_bf16_kernel(
    const float* __restrict__ x, const float* __restrict__ gw,
    const float* __restrict__ bw, u16* __restrict__ out)
{
  int row = blockIdx.x;
  int lane = threadIdx.x;
  const float* xr = x + (size_t)row * DM;
  float4 v0 = ((const float4*)xr)[lane];
  float4 v1 = ((const float4*)xr)[lane + 64];
  float s  = v0.x + v0.y + v0.z + v0.w + v1.x + v1.y + v1.z + v1.w;
  float s2 = v0.x*v0.x + v0.y*v0.y + v0.z*v0.z + v0.w*v0.w
           + v1.x*v1.x + v1.y*v1.y + v1.z*v1.z + v1.w*v1.w;
  #pragma unroll
  for (int m = 1; m < 64; m <<= 1) {
    s  += __shfl_xor(s,  m);
    s2 += __shfl_xor(s2, m);
  }
  float mu   = s * (1.0f / DM);
  float var  = s2 * (1.0f / DM) - mu * mu;
  float rstd = rsqrtf(var + 1e-5f);
  float4 ga = ((const float4*)gw)[lane],      ba = ((const float4*)bw)[lane];
  float4 gb = ((const float4*)gw)[lane + 64], bb = ((const float4*)bw)[lane + 64];
  ushort4 o0, o1;
  o0.x = f2bf((v0.x - mu) * rstd * ga.x + ba.x);
  o0.y = f2bf((v0.y - mu) * rstd * ga.y + ba.y);
  o0.z = f2bf((v0.z - mu) * rstd * ga.z + ba.z);
  o0.w = f2bf((v0.w - mu) * rstd * ga.w + ba.w);
  o1.x = f2bf((v1.x - mu) * rstd * gb.x + bb.x);
  o1.y = f2bf((v1.y - mu) * rstd * gb.y + bb.y);
  o1.z = f2bf((v1.z - mu) * rstd * gb.z + bb.z);
  o1.w = f2bf((v1.w - mu) * rstd * gb.w + bb.w);
  *(ushort4*)&out[(size_t)row * DM + lane * 4]       = o0;
  *(ushort4*)&out[(size_t)row * DM + 256 + lane * 4] = o1;
}

// ---------------- Transpose + cast fp32 (K x N) -> bf16 (N x K) ------------
__global__ __launch_bounds__(256) void transpose_cast_kernel(
    const float* __restrict__ W, u16* __restrict__ Wt, int K, int N)
{
  __shared__ float tile[32][33];
  int bn = blockIdx.x * 32, bk = blockIdx.y * 32;
  int tx = threadIdx.x & 31, ty = threadIdx.x >> 5; // 32 x 8
  #pragma unroll
  for (int i = 0; i < 32; i += 8)
    tile[ty + i][tx] = W[(size_t)(bk + ty + i) * N + bn + tx];
  __syncthreads();
  #pragma unroll
  for (int i = 0; i < 32; i += 8)
    Wt[(size_t)(bn + ty + i) * K + bk + tx] = f2bf(tile[tx][ty + i]);
}

// ---------------- Elementwise cast fp32 -> bf16 ----------------------------
__global__ __launch_bounds__(256) void cast_bf16_kernel(
    const float* __restrict__ in, u16* __restrict__ out, int n)
{
  int i = (blockIdx.x * 256 + threadIdx.x) * 4;
  if (i >= n) return;
  float4 v = *(const float4*)&in[i];
  ushort4 o;
  o.x = f2bf(v.x); o.y = f2bf(v.y); o.z = f2bf(v.z); o.w = f2bf(v.w);
  *(ushort4*)&out[i] = o;
}

// ---------------- TMxTN MFMA GEMM, BK=64, counted-vmcnt 2-phase pipeline ---
// 1-D grid (nwg % 8 == 0), bijective XCD swizzle. Per K-step:
// barrier -> stage(next buf) -> vmcnt(LOADS) [waits PREVIOUS stage only]
// -> barrier -> MFMA(cur buf). Never drains the in-flight prefetch.
template<int TM, int TN, int MODE>
__global__ __launch_bounds__(256) void gemm_bf16(
    const u16* __restrict__ A, const u16* __restrict__ Bt,
    const float* __restrict__ bias, const float* __restrict__ res,
    float* __restrict__ outF, u16* __restrict__ outB0,
    u16* __restrict__ outB1, u16* __restrict__ outB2,
    int M, int N, int K)
{
  constexpr int MI = TM / 32;       // m-frags per wave
  constexpr int NI = TN / 32;       // n-frags per wave
  constexpr int LOADS = TM / 32 + TN / 32;  // gll16 per thread per stage
  __shared__ u16 sA[2][TM * 64];
  __shared__ u16 sB[2][TN * 64];
  int tid = threadIdx.x;
  int lane = tid & 63, wv = tid >> 6;
  int wm = wv >> 1, wn = wv & 1;
  int g = lane >> 4, l15 = lane & 15;

  int nwg = gridDim.x, lin = blockIdx.x;
  int qq = nwg >> 3;
  int wg = (lin & 7) * qq + (lin >> 3);     // bijective: nwg % 8 == 0
  int ntn = N / TN;
  int m0 = (wg / ntn) * TM, n0 = (wg % ntn) * TN;

  auto stage = [&](int buf, int k0) {
    #pragma unroll
    for (int s = 0; s < TM / 32; ++s) {     // A: TM rows x 8 chunks
      int c = s * 256 + tid;
      int row = c >> 3, p = c & 7;
      gll16(&A[(size_t)(m0 + row) * K + k0 + ((p ^ (row & 7)) * 8)],
            &sA[buf][(size_t)(s * 256 + wv * 64) * 8]);
    }
    #pragma unroll
    for (int s = 0; s < TN / 32; ++s) {     // B: TN rows x 8 chunks
      int c = s * 256 + tid;
      int row = c >> 3, p = c & 7;
      gll16(&Bt[(size_t)(n0 + row) * K + k0 + ((p ^ (row & 7)) * 8)],
            &sB[buf][(size_t)(s * 256 + wv * 64) * 8]);
    }
  };

  f32x4 acc[MI][NI] = {};
  stage(0, 0);

  int nk = K / 64;
  for (int kt = 0; kt < nk; ++kt) {
    int cur = kt & 1;
    __syncthreads();                         // buf cur^1 reads (prev compute) done
    if (kt + 1 < nk) {
      stage(cur ^ 1, (kt + 1) * 64);         // prefetch into freed buffer
      waitcnt_vm<LOADS>();                   // wait only for PREVIOUS stage
    } else {
      waitcnt_vm<0>();
    }
    __syncthreads();                         // buf cur visible to all waves
    #pragma unroll
    for (int kk = 0; kk < 2; ++kk) {
      short8 af[MI], bfr[NI];
      #pragma unroll
      for (int i = 0; i < MI; ++i) {
        int row = wm * (TM / 2) + i * 16 + l15;
        af[i] = *(const short8*)&sA[cur][row * 64 + (((4 * kk + g) ^ (row & 7)) * 8)];
      }
      #pragma unroll
      for (int i = 0; i < NI; ++i) {
        int row = wn * (TN / 2) + i * 16 + l15;
        bfr[i] = *(const short8*)&sB[cur][row * 64 + (((4 * kk + g) ^ (row & 7)) * 8)];
      }
      #pragma unroll
      for (int mi = 0; mi < MI; ++mi)
        #pragma unroll
        for (int ni = 0; ni < NI; ++ni)
          acc[mi][ni] = __builtin_amdgcn_mfma_f32_16x16x32_bf16(af[mi], bfr[ni], acc[mi][ni], 0, 0, 0);
    }
  }

  #pragma unroll
  for (int mi = 0; mi < MI; ++mi) {
    #pragma unroll
    for (int ni = 0; ni < NI; ++ni) {
      #pragma unroll
      for (int r = 0; r < 4; ++r) {
        int grow = m0 + wm * (TM / 2) + mi * 16 + g * 4 + r;
        int gcol = n0 + wn * (TN / 2) + ni * 16 + l15;
        float val = acc[mi][ni][r] + bias[gcol];
        if (MODE == 0) {
          int part = gcol >> 9, c = gcol & 511;
          int hh = c >> 6, dd = c & 63;
          int bb = grow >> 11, ss = grow & 2047;
          size_t dst = (((size_t)(bb * NH + hh)) * SEQ + ss) * DH + dd;
          if (part == 0)      outB0[dst] = f2bf(val * 0.18033688011112042f); // q * 0.125*log2(e)
          else if (part == 1) outB1[dst] = f2bf(val);           // k
          else                outB2[dst] = f2bf(val);           // v
        } else if (MODE == 1 || MODE == 3) {
          size_t idx = (size_t)grow * DM + gcol;
          outF[idx] = val + res[idx];
        } else { // MODE 2: gelu (tanh approx = jax.nn.gelu default)
          float t = val;
          float inner = 0.7978845608028654f * (t + 0.044715f * t * t * t);
          float gl = 0.5f * t * (1.0f + tanhf(inner));
          outB0[(size_t)grow * N + gcol] = f2bf(gl);
        }
      }
    }
  }
}

// ---------------- Flash causal attention with relative positions -----------
// R4 decomposition, single-buffered K, + bijective XCD swizzle: each XCD
// gets 64 contiguous wg = exactly 2 bh, whose K/V/E/Q (~2.5MB) fit the 4MB
// per-XCD L2 -> K/V/E fetched ~once per XCD instead of ~8x (FETCH 90->~20MB).
__global__ __launch_bounds__(256, 2) void attn_kernel(
    const u16* __restrict__ Q, const u16* __restrict__ Kb,
    const u16* __restrict__ Vb, const u16* __restrict__ Eb,
    u16* __restrict__ Ob)
{
  __shared__ u16 sK[KVB * 64];           // 16KB, chunk-swizzled linear (gll)
  __shared__ u16 sV[64 * (KVB + 8)];     // 17.4KB, [d][t] block-XOR, single
  __shared__ u16 sP[4][16 * 64];         // 8KB, per-wave (sO overlays)
  __shared__ float sM[2][32];            // cross-half max exchange
  __shared__ float sS[2][32];            // cross-half sum exchange

  int tid = threadIdx.x, lane = tid & 63, wv = tid >> 6;
  int wr = wv & 1, wc = wv >> 1;
  int g = lane >> 4, l15 = lane & 15;
  int lin = blockIdx.x;
  int blk = (lin & 7) * 64 + (lin >> 3);  // bijective XCD swizzle (512 % 8 == 0)
  int bh = blk >> 5, pp = blk & 31;
  int hh = bh & (NH - 1), bb = bh >> 3;

  const u16* Qh = Q  + (size_t)bh * SEQ * DH;
  const u16* Kh = Kb + (size_t)bh * SEQ * DH;
  const u16* Vh = Vb + (size_t)bh * SEQ * DH;
  const u16* Eh = Eb + (size_t)hh * SEQ * DH;

  int tileA = pp, tileB = 63 - pp;
  int itersA = pp / 4 + 1;
  const int TOT = 17;

  int rstage = tid >> 3, cstage = (tid & 7) * 8;

  // ---- prologue: stage kt=0 ----
  #pragma unroll
  for (int s = 0; s < 4; ++s) {
    int c = s * 256 + tid, t = c >> 3, pc = c & 7;
    gll16(&Kh[(size_t)t * DH + ((pc ^ (t & 7)) * 8)],
          &sK[(size_t)(s * 256 + wv * 64) * 8]);
  }
  #pragma unroll
  for (int q = 0; q < 4; ++q) {
    int t = q * 32 + rstage;
    short8 vv = *(const short8*)&Vh[(size_t)t * DH + cstage];
    #pragma unroll
    for (int j = 0; j < 8; ++j) {
      int d = cstage + j;
      sV[d * (KVB + 8) + (((t >> 3) ^ (d >> 3)) * 8) + (t & 7)] = (u16)vv[j];
    }
  }
  asm volatile("s_waitcnt vmcnt(0)" ::: "memory");
  __syncthreads();

  short8 qf[2];
  {
    int sw = tileA * 32 + wr * 16;
    qf[0] = *(const short8*)&Qh[(size_t)(sw + l15) * DH + g * 8];
    qf[1] = *(const short8*)&Qh[(size_t)(sw + l15) * DH + g * 8 + 32];
  }
  f32x4 o[4] = {};
  float mrow[4] = {-1e30f, -1e30f, -1e30f, -1e30f};
  float lsum[4] = {};

  float* sO = (float*)&sP[0][0];   // [2][16][64] f32 overlay at flush time

  auto flushOut = [&](int tile) {
    int swt = tile * 32 + wr * 16;
    if (wc == 1) {
      #pragma unroll
      for (int r = 0; r < 4; ++r) {
        float rl = 1.0f / lsum[r];
        #pragma unroll
        for (int nb = 0; nb < 4; ++nb)
          sO[wr * 1024 + (g * 4 + r) * 64 + nb * 16 + l15] = o[nb][r] * rl;
      }
    }
    __syncthreads();
    if (wc == 0) {
      #pragma unroll
      for (int r = 0; r < 4; ++r) {
        float rl = 1.0f / lsum[r];
        int ss = swt + g * 4 + r;
        #pragma unroll
        for (int nb = 0; nb < 4; ++nb) {
          float val = o[nb][r] * rl + sO[wr * 1024 + (g * 4 + r) * 64 + nb * 16 + l15];
          Ob[((size_t)(bb * SEQ + ss)) * DM + hh * DH + nb * 16 + l15] = f2bf(val);
        }
      }
    }
  };

  for (int it = 0; it < TOT; ++it) {
    if (it == itersA) {
      flushOut(tileA);
      #pragma unroll
      for (int nb = 0; nb < 4; ++nb) o[nb] = f32x4{};
      #pragma unroll
      for (int r = 0; r < 4; ++r) { mrow[r] = -1e30f; lsum[r] = 0.f; }
      int sw = tileB * 32 + wr * 16;
      qf[0] = *(const short8*)&Qh[(size_t)(sw + l15) * DH + g * 8];
      qf[1] = *(const short8*)&Qh[(size_t)(sw + l15) * DH + g * 8 + 32];
    }
    int tile = (it < itersA) ? tileA : tileB;
    int kt   = (it < itersA) ? it : it - itersA;
    int sw = tile * 32 + wr * 16, t0 = kt * KVB;

    // prefetch next V into regs (issue at top: longest latency window)
    bool pre = (it + 1 < TOT);
    int tb = 0;
    short8 vp[4];
    if (pre) {
      int kn = (it + 1 < itersA) ? it + 1 : it + 1 - itersA;
      tb = kn * KVB;
      #pragma unroll
      for (int q = 0; q < 4; ++q)
        vp[q] = *(const short8*)&Vh[(size_t)(tb + q * 32 + rstage) * DH + cstage];
    }

    // S1 = Q K^T (16 rows x 64 cols per wave, this wave's column half)
    f32x4 accS[4];
    #pragma unroll
    for (int ni = 0; ni < 4; ++ni) {
      int row = wc * 64 + ni * 16 + l15;
      short8 k0 = *(const short8*)&sK[row * 64 + ((g ^ (row & 7)) * 8)];
      short8 k1 = *(const short8*)&sK[row * 64 + (((4 + g) ^ (row & 7)) * 8)];
      f32x4 z = {};
      z = __builtin_amdgcn_mfma_f32_16x16x32_bf16(qf[0], k0, z, 0, 0, 0);
      z = __builtin_amdgcn_mfma_f32_16x16x32_bf16(qf[1], k1, z, 0, 0, 0);
      accS[ni] = z;
    }

    // S2 = Q E^T strip (16 x 80): rel[s,t] = q[s].E[2047 - s + t]
    int jbase = 2032 - sw + t0 + wc * 64;
    f32x4 accR[5];
    #pragma unroll
    for (int nb = 0; nb < 5; ++nb) {
      int j = jbase + nb * 16 + l15; if (j > 2047) j = 2047;
      short8 e0 = *(const short8*)&Eh[(size_t)j * DH + g * 8];
      short8 e1 = *(const short8*)&Eh[(size_t)j * DH + 32 + g * 8];
      f32x4 z = {};
      z = __builtin_amdgcn_mfma_f32_16x16x32_bf16(qf[0], e0, z, 0, 0, 0);
      z = __builtin_amdgcn_mfma_f32_16x16x32_bf16(qf[1], e1, z, 0, 0, 0);
      accR[nb] = z;
    }

    // skew realign + combine + causal mask
    bool needMask = (t0 + wc * 64 + 63 > sw);
    #pragma unroll
    for (int r = 0; r < 4; ++r) {
      int srow = g * 4 + r;
      int dsh = 15 - srow + l15;                 // 0..30
      int srcl = (lane & 48) + (dsh & 15);
      float sh[5];
      #pragma unroll
      for (int nb = 0; nb < 5; ++nb) sh[nb] = __shfl(accR[nb][r], srcl);
      bool cy = dsh >= 16;
      #pragma unroll
      for (int ni = 0; ni < 4; ++ni) {
        float rel = cy ? sh[ni + 1] : sh[ni];
        float val = accS[ni][r] + rel;
        if (needMask && (t0 + wc * 64 + ni * 16 + l15 > sw + srow)) val = -1e30f;
        accS[ni][r] = val;
      }
    }

    // local row max -> exchange across column halves
    float lmax[4];
    #pragma unroll
    for (int r = 0; r < 4; ++r) {
      float tm = fmaxf(fmaxf(accS[0][r], accS[1][r]), fmaxf(accS[2][r], accS[3][r]));
      tm = fmaxf(tm, __shfl_xor(tm, 1));
      tm = fmaxf(tm, __shfl_xor(tm, 2));
      tm = fmaxf(tm, __shfl_xor(tm, 4));
      tm = fmaxf(tm, __shfl_xor(tm, 8));
      lmax[r] = tm;
    }
    if (l15 == 0) {
      #pragma unroll
      for (int r = 0; r < 4; ++r) sM[wc][wr * 16 + g * 4 + r] = lmax[r];
    }
    __syncthreads();                              // B1: all sK reads done
    // issue next K tile into the SAME sK buffer (drained at B2)
    if (pre) {
      #pragma unroll
      for (int s = 0; s < 4; ++s) {
        int c = s * 256 + tid, t = c >> 3, pc = c & 7;
        gll16(&Kh[(size_t)(tb + t) * DH + ((pc ^ (t & 7)) * 8)],
              &sK[(size_t)(s * 256 + wv * 64) * 8]);
      }
    }
    float4 om = *(float4*)&sM[wc ^ 1][wr * 16 + g * 4];

    // global max -> rescale o, exp, local sums
    float sesav[4], lscl[4];
    #pragma unroll
    for (int r = 0; r < 4; ++r) {
      float gm = fmaxf(lmax[r], ((float*)&om)[r]);
      float mnew = fmaxf(mrow[r], gm);
      lscl[r] = exp2f(mrow[r] - mnew);
      mrow[r] = mnew;
      float se = 0.f;
      #pragma unroll
      for (int ni = 0; ni < 4; ++ni) {
        float pe = exp2f(accS[ni][r] - mnew);
        accS[ni][r] = pe;
        se += pe;
      }
      se += __shfl_xor(se, 1); se += __shfl_xor(se, 2);
      se += __shfl_xor(se, 4); se += __shfl_xor(se, 8);
      sesav[r] = se;
      o[0][r] *= lscl[r]; o[1][r] *= lscl[r]; o[2][r] *= lscl[r]; o[3][r] *= lscl[r];
    }
    if (l15 == 0) {
      #pragma unroll
      for (int r = 0; r < 4; ++r) sS[wc][wr * 16 + g * 4 + r] = sesav[r];
    }

    // P -> per-wave LDS, then PV (accumulates into rescaled o)
    #pragma unroll
    for (int ni = 0; ni < 4; ++ni)
      #pragma unroll
      for (int r = 0; r < 4; ++r) {
        int srow = g * 4 + r;
        int chunk = (ni * 2 + (l15 >> 3)) ^ (srow & 7);
        sP[wv][srow * 64 + chunk * 8 + (l15 & 7)] = f2bf(accS[ni][r]);
      }
    asm volatile("s_waitcnt lgkmcnt(0)" ::: "memory");
    __builtin_amdgcn_sched_barrier(0);
    #pragma unroll
    for (int kk = 0; kk < 2; ++kk) {
      short8 pf = *(const short8*)&sP[wv][l15 * 64 + (((kk * 4 + g) ^ (l15 & 7)) * 8)];
      #pragma unroll
      for (int nb = 0; nb < 4; ++nb) {
        int d = nb * 16 + l15;
        int ck = wc * 8 + kk * 4 + g;
        short8 vf = *(const short8*)&sV[d * (KVB + 8) + ((ck ^ (d >> 3)) * 8)];
        o[nb] = __builtin_amdgcn_mfma_f32_16x16x32_bf16(pf, vf, o[nb], 0, 0, 0);
      }
    }

    __syncthreads();                              // B2 (drains vm+lgkm: K staged)
    float4 os = *(float4*)&sS[wc ^ 1][wr * 16 + g * 4];
    #pragma unroll
    for (int r = 0; r < 4; ++r)
      lsum[r] = lsum[r] * lscl[r] + sesav[r] + ((float*)&os)[r];

    // write prefetched V^T into sV (reads of this iter are done; next
    // iteration's B1 orders these writes before its PV reads)
    if (pre) {
      #pragma unroll
      for (int q = 0; q < 4; ++q) {
        int t = q * 32 + rstage;
        #pragma unroll
        for (int j = 0; j < 8; ++j) {
          int d = cstage + j;
          sV[d * (KVB + 8) + (((t >> 3) ^ (d >> 3)) * 8) + (t & 7)] = (u16)vp[q][j];
        }
      }
    }
  }

  flushOut(tileB);
}

// ---------------------------------------------------------------------------
extern "C" void kernel_launch(void* const* d_in, const int* in_sizes, int n_in,
                              void* d_out, int out_size, void* d_ws, size_t ws_size,
                              hipStream_t stream) {
  const float* x     = (const float*)d_in[0];
  // d_in[1] = mask: recomputed causally in-kernel
  const float* Wqkv  = (const float*)d_in[2];
  const float* bqkv  = (const float*)d_in[3];
  const float* Wproj = (const float*)d_in[4];
  const float* bproj = (const float*)d_in[5];
  const float* E     = (const float*)d_in[6];
  const float* g1    = (const float*)d_in[7];
  const float* b1    = (const float*)d_in[8];
  const float* g2    = (const float*)d_in[9];
  const float* b2    = (const float*)d_in[10];
  const float* W1    = (const float*)d_in[11];
  const float* bm1   = (const float*)d_in[12];
  const float* W2    = (const float*)d_in[13];
  const float* bm2   = (const float*)d_in[14];
  float* out = (float*)d_out;

  char* ws = (char*)d_ws;
  size_t off = 0;
  auto alloc = [&](size_t bytes) {
    void* p = ws + off;
    off += (bytes + 255) & ~(size_t)255;
    return p;
  };
  u16* a_bf   = (u16*)alloc((size_t)NROWS * DM * 2);      // LN1 out, reused for LN2 out
  u16* q_bf   = (u16*)alloc((size_t)NROWS * DM * 2);
  u16* k_bf   = (u16*)alloc((size_t)NROWS * DM * 2);
  u16* v_bf   = (u16*)alloc((size_t)NROWS * DM * 2);
  u16* att_bf = (u16*)alloc((size_t)NROWS * DM * 2);
  float* y    = (float*)alloc((size_t)NROWS * DM * 4);
  u16* h_bf   = (u16*)alloc((size_t)NROWS * 2048 * 2);
  u16* WqkvT  = (u16*)alloc((size_t)1536 * 512 * 2);
  u16* WprojT = (u16*)alloc((size_t)512 * 512 * 2);
  u16* W1T    = (u16*)alloc((size_t)2048 * 512 * 2);
  u16* W2T    = (u16*)alloc((size_t)512 * 2048 * 2);
  u16* E_bf   = (u16*)alloc((size_t)NH * SEQ * DH * 2);

  // weights -> bf16 (transposed to N x K)
  transpose_cast_kernel<<<dim3(1536 / 32, 512 / 32), 256, 0, stream>>>(Wqkv, WqkvT, 512, 1536);
  transpose_cast_kernel<<<dim3(512 / 32, 512 / 32), 256, 0, stream>>>(Wproj, WprojT, 512, 512);
  transpose_cast_kernel<<<dim3(2048 / 32, 512 / 32), 256, 0, stream>>>(W1, W1T, 512, 2048);
  transpose_cast_kernel<<<dim3(512 / 32, 2048 / 32), 256, 0, stream>>>(W2, W2T, 2048, 512);
  cast_bf16_kernel<<<(NH * SEQ * DH) / (256 * 4), 256, 0, stream>>>(E, E_bf, NH * SEQ * DH);

  // LN1
  ln_bf16_kernel<<<NROWS, 64, 0, stream>>>(x, g1, b1, a_bf);
  // QKV (q pre-scaled by 0.125*log2e); grid 768 = 64x12 (3/CU)
  gemm_bf16<64, 128, 0><<<(NROWS / 64) * (1536 / 128), 256, 0, stream>>>(
      a_bf, WqkvT, bqkv, nullptr, nullptr, q_bf, k_bf, v_bf, NROWS, 1536, 512);
  // attention (R4 decomposition + XCD-swizzled grid)
  attn_kernel<<<512, 256, 0, stream>>>(q_bf, k_bf, v_bf, E_bf, att_bf);
  // proj + residual -> y (fp32); grid 512 = 64x8
  gemm_bf16<64, 64, 1><<<(NROWS / 64) * (512 / 64), 256, 0, stream>>>(
      att_bf, WprojT, bproj, x, y, nullptr, nullptr, nullptr, NROWS, 512, 512);
  // LN2 (reuse a_bf as m_bf)
  ln_bf16_kernel<<<NROWS, 64, 0, stream>>>(y, g2, b2, a_bf);
  // FFN1 + gelu; grid 1024 = 64x16 (4/CU)
  gemm_bf16<64, 128, 2><<<(NROWS / 64) * (2048 / 128), 256, 0, stream>>>(
      a_bf, W1T, bm1, nullptr, nullptr, h_bf, nullptr, nullptr, NROWS, 2048, 512);
  // FFN2 + residual -> out; grid 512 = 64x8, 32 K-steps
  gemm_bf16<64, 64, 3><<<(NROWS / 64) * (512 / 64), 256, 0, stream>>>(
      h_bf, W2T, bm2, y, out, nullptr, nullptr, nullptr, NROWS, 512, 2048);
}

// Round 11
// 168.129 us; speedup vs baseline: 1.4897x; 1.0035x over previous
//
#include <hip/hip_runtime.h>
#include <math.h>

typedef unsigned short u16;
typedef unsigned int u32;
using short8 = __attribute__((ext_vector_type(8))) short;
using f32x4  = __attribute__((ext_vector_type(4))) float;

#define SEQ 2048
#define NH 8
#define DM 512
#define DH 64
#define NROWS 4096  // B*S
#define BATCH 2
#define KVB 128

__device__ __forceinline__ float bf2f(u16 u) {
  union { u32 i; float f; } c; c.i = ((u32)u) << 16; return c.f;
}
__device__ __forceinline__ u16 f2bf(float f) {
  union { float f; u32 i; } c; c.f = f;
  u32 r = c.i + 0x7fffu + ((c.i >> 16) & 1u);
  return (u16)(r >> 16);
}

// async global->LDS, 16B per lane. LDS dest must be wave-uniform base.
__device__ __forceinline__ void gll16(const u16* g, u16* l) {
  __builtin_amdgcn_global_load_lds(
      (const __attribute__((address_space(1))) u32*)g,
      (__attribute__((address_space(3))) u32*)l, 16, 0, 0);
}

template<int N> __device__ __forceinline__ void waitcnt_vm() {
  if constexpr (N == 0)      asm volatile("s_waitcnt vmcnt(0)" ::: "memory");
  else if constexpr (N == 4) asm volatile("s_waitcnt vmcnt(4)" ::: "memory");
  else if constexpr (N == 6) asm volatile("s_waitcnt vmcnt(6)" ::: "memory");
  else if constexpr (N == 8) asm volatile("s_waitcnt vmcnt(8)" ::: "memory");
}

// ---------------- LayerNorm (fp32 in -> bf16 out), one wave per 512-row ----
__global__ __launch_bounds__(64) void ln_bf16_kernel(
    const float* __restrict__ x, const float* __restrict__ gw,
    const float* __restrict__ bw, u16* __restrict__ out)
{
  int row = blockIdx.x;
  int lane = threadIdx.x;
  const float* xr = x + (size_t)row * DM;
  float4 v0 = ((const float4*)xr)[lane];
  float4 v1 = ((const float4*)xr)[lane + 64];
  float s  = v0.x + v0.y + v0.z + v0.w + v1.x + v1.y + v1.z + v1.w;
  float s2 = v0.x*v0.x + v0.y*v0.y + v0.z*v0.z + v0.w*v0.w
           + v1.x*v1.x + v1.y*v1.y + v1.z*v1.z + v1.w*v1.w;
  #pragma unroll
  for (int m = 1; m < 64; m <<= 1) {
    s  += __shfl_xor(s,  m);
    s2 += __shfl_xor(s2, m);
  }
  float mu   = s * (1.0f / DM);
  float var  = s2 * (1.0f / DM) - mu * mu;
  float rstd = rsqrtf(var + 1e-5f);
  float4 ga = ((const float4*)gw)[lane],      ba = ((const float4*)bw)[lane];
  float4 gb = ((const float4*)gw)[lane + 64], bb = ((const float4*)bw)[lane + 64];
  ushort4 o0, o1;
  o0.x = f2bf((v0.x - mu) * rstd * ga.x + ba.x);
  o0.y = f2bf((v0.y - mu) * rstd * ga.y + ba.y);
  o0.z = f2bf((v0.z - mu) * rstd * ga.z + ba.z);
  o0.w = f2bf((v0.w - mu) * rstd * ga.w + ba.w);
  o1.x = f2bf((v1.x - mu) * rstd * gb.x + bb.x);
  o1.y = f2bf((v1.y - mu) * rstd * gb.y + bb.y);
  o1.z = f2bf((v1.z - mu) * rstd * gb.z + bb.z);
  o1.w = f2bf((v1.w - mu) * rstd * gb.w + bb.w);
  *(ushort4*)&out[(size_t)row * DM + lane * 4]       = o0;
  *(ushort4*)&out[(size_t)row * DM + 256 + lane * 4] = o1;
}

// ---------------- Transpose + cast fp32 (K x N) -> bf16 (N x K) ------------
__global__ __launch_bounds__(256) void transpose_cast_kernel(
    const float* __restrict__ W, u16* __restrict__ Wt, int K, int N)
{
  __shared__ float tile[32][33];
  int bn = blockIdx.x * 32, bk = blockIdx.y * 32;
  int tx = threadIdx.x & 31, ty = threadIdx.x >> 5; // 32 x 8
  #pragma unroll
  for (int i = 0; i < 32; i += 8)
    tile[ty + i][tx] = W[(size_t)(bk + ty + i) * N + bn + tx];
  __syncthreads();
  #pragma unroll
  for (int i = 0; i < 32; i += 8)
    Wt[(size_t)(bn + ty + i) * K + bk + tx] = f2bf(tile[tx][ty + i]);
}

// ---------------- Elementwise cast fp32 -> bf16 ----------------------------
__global__ __launch_bounds__(256) void cast_bf16_kernel(
    const float* __restrict__ in, u16* __restrict__ out, int n)
{
  int i = (blockIdx.x * 256 + threadIdx.x) * 4;
  if (i >= n) return;
  float4 v = *(const float4*)&in[i];
  ushort4 o;
  o.x = f2bf(v.x); o.y = f2bf(v.y); o.z = f2bf(v.z); o.w = f2bf(v.w);
  *(ushort4*)&out[i] = o;
}

// ---------------- TMxTN MFMA GEMM, BK=64, counted-vmcnt 2-phase pipeline ---
// 1-D grid (nwg % 8 == 0), bijective XCD swizzle. Per K-step:
// barrier -> stage(next buf) -> vmcnt(LOADS) [waits PREVIOUS stage only]
// -> barrier -> MFMA(cur buf). Never drains the in-flight prefetch.
template<int TM, int TN, int MODE>
__global__ __launch_bounds__(256) void gemm_bf16(
    const u16* __restrict__ A, const u16* __restrict__ Bt,
    const float* __restrict__ bias, const float* __restrict__ res,
    float* __restrict__ outF, u16* __restrict__ outB0,
    u16* __restrict__ outB1, u16* __restrict__ outB2,
    int M, int N, int K)
{
  constexpr int MI = TM / 32;       // m-frags per wave
  constexpr int NI = TN / 32;       // n-frags per wave
  constexpr int LOADS = TM / 32 + TN / 32;  // gll16 per thread per stage
  __shared__ u16 sA[2][TM * 64];
  __shared__ u16 sB[2][TN * 64];
  int tid = threadIdx.x;
  int lane = tid & 63, wv = tid >> 6;
  int wm = wv >> 1, wn = wv & 1;
  int g = lane >> 4, l15 = lane & 15;

  int nwg = gridDim.x, lin = blockIdx.x;
  int qq = nwg >> 3;
  int wg = (lin & 7) * qq + (lin >> 3);     // bijective: nwg % 8 == 0
  int ntn = N / TN;
  int m0 = (wg / ntn) * TM, n0 = (wg % ntn) * TN;

  auto stage = [&](int buf, int k0) {
    #pragma unroll
    for (int s = 0; s < TM / 32; ++s) {     // A: TM rows x 8 chunks
      int c = s * 256 + tid;
      int row = c >> 3, p = c & 7;
      gll16(&A[(size_t)(m0 + row) * K + k0 + ((p ^ (row & 7)) * 8)],
            &sA[buf][(size_t)(s * 256 + wv * 64) * 8]);
    }
    #pragma unroll
    for (int s = 0; s < TN / 32; ++s) {     // B: TN rows x 8 chunks
      int c = s * 256 + tid;
      int row = c >> 3, p = c & 7;
      gll16(&Bt[(size_t)(n0 + row) * K + k0 + ((p ^ (row & 7)) * 8)],
            &sB[buf][(size_t)(s * 256 + wv * 64) * 8]);
    }
  };

  f32x4 acc[MI][NI] = {};
  stage(0, 0);

  int nk = K / 64;
  for (int kt = 0; kt < nk; ++kt) {
    int cur = kt & 1;
    __syncthreads();                         // buf cur^1 reads (prev compute) done
    if (kt + 1 < nk) {
      stage(cur ^ 1, (kt + 1) * 64);         // prefetch into freed buffer
      waitcnt_vm<LOADS>();                   // wait only for PREVIOUS stage
    } else {
      waitcnt_vm<0>();
    }
    __syncthreads();                         // buf cur visible to all waves
    #pragma unroll
    for (int kk = 0; kk < 2; ++kk) {
      short8 af[MI], bfr[NI];
      #pragma unroll
      for (int i = 0; i < MI; ++i) {
        int row = wm * (TM / 2) + i * 16 + l15;
        af[i] = *(const short8*)&sA[cur][row * 64 + (((4 * kk + g) ^ (row & 7)) * 8)];
      }
      #pragma unroll
      for (int i = 0; i < NI; ++i) {
        int row = wn * (TN / 2) + i * 16 + l15;
        bfr[i] = *(const short8*)&sB[cur][row * 64 + (((4 * kk + g) ^ (row & 7)) * 8)];
      }
      #pragma unroll
      for (int mi = 0; mi < MI; ++mi)
        #pragma unroll
        for (int ni = 0; ni < NI; ++ni)
          acc[mi][ni] = __builtin_amdgcn_mfma_f32_16x16x32_bf16(af[mi], bfr[ni], acc[mi][ni], 0, 0, 0);
    }
  }

  #pragma unroll
  for (int mi = 0; mi < MI; ++mi) {
    #pragma unroll
    for (int ni = 0; ni < NI; ++ni) {
      #pragma unroll
      for (int r = 0; r < 4; ++r) {
        int grow = m0 + wm * (TM / 2) + mi * 16 + g * 4 + r;
        int gcol = n0 + wn * (TN / 2) + ni * 16 + l15;
        float val = acc[mi][ni][r] + bias[gcol];
        if (MODE == 0) {
          int part = gcol >> 9, c = gcol & 511;
          int hh = c >> 6, dd = c & 63;
          int bb = grow >> 11, ss = grow & 2047;
          size_t dst = (((size_t)(bb * NH + hh)) * SEQ + ss) * DH + dd;
          if (part == 0)      outB0[dst] = f2bf(val * 0.18033688011112042f); // q * 0.125*log2(e)
          else if (part == 1) outB1[dst] = f2bf(val);           // k
          else                outB2[dst] = f2bf(val);           // v
        } else if (MODE == 1 || MODE == 3) {
          size_t idx = (size_t)grow * DM + gcol;
          outF[idx] = val + res[idx];
        } else { // MODE 2: gelu (tanh approx = jax.nn.gelu default)
          float t = val;
          float inner = 0.7978845608028654f * (t + 0.044715f * t * t * t);
          float gl = 0.5f * t * (1.0f + tanhf(inner));
          outB0[(size_t)grow * N + gcol] = f2bf(gl);
        }
      }
    }
  }
}

// ---------------- Flash causal attention with relative positions -----------
// Variable-length schedule: 1024 blocks = (16 bh x 64 single 32-row q-tiles).
// tile = 63 - (lin>>4): longest blocks dispatched FIRST (short ones backfill).
// bh = (lin&7)*2 + ((lin>>3)&1): 2 bh per XCD under blk%8 round-robin ->
// K/V/E stay L2-local (R10: FETCH 90->8.3MB). LDS 42.5KB -> 3 blocks/CU.
// Inner iteration body identical to R10's (4 waves = 2 row x 2 col halves).
__global__ __launch_bounds__(256, 2) void attn_kernel(
    const u16* __restrict__ Q, const u16* __restrict__ Kb,
    const u16* __restrict__ Vb, const u16* __restrict__ Eb,
    u16* __restrict__ Ob)
{
  __shared__ u16 sK[KVB * 64];           // 16KB, chunk-swizzled linear (gll)
  __shared__ u16 sV[64 * (KVB + 8)];     // 17.4KB, [d][t] block-XOR, single
  __shared__ u16 sP[4][16 * 64];         // 8KB, per-wave (sO overlays)
  __shared__ float sM[2][32];            // cross-half max exchange
  __shared__ float sS[2][32];            // cross-half sum exchange

  int tid = threadIdx.x, lane = tid & 63, wv = tid >> 6;
  int wr = wv & 1, wc = wv >> 1;
  int g = lane >> 4, l15 = lane & 15;
  int lin = blockIdx.x;
  int bh   = (lin & 7) * 2 + ((lin >> 3) & 1);
  int tile = 63 - (lin >> 4);
  int hh = bh & (NH - 1), bb = bh >> 3;
  int NIT = tile / 4 + 1;

  const u16* Qh = Q  + (size_t)bh * SEQ * DH;
  const u16* Kh = Kb + (size_t)bh * SEQ * DH;
  const u16* Vh = Vb + (size_t)bh * SEQ * DH;
  const u16* Eh = Eb + (size_t)hh * SEQ * DH;

  int rstage = tid >> 3, cstage = (tid & 7) * 8;

  // ---- prologue: stage kt=0 ----
  #pragma unroll
  for (int s = 0; s < 4; ++s) {
    int c = s * 256 + tid, t = c >> 3, pc = c & 7;
    gll16(&Kh[(size_t)t * DH + ((pc ^ (t & 7)) * 8)],
          &sK[(size_t)(s * 256 + wv * 64) * 8]);
  }
  #pragma unroll
  for (int q = 0; q < 4; ++q) {
    int t = q * 32 + rstage;
    short8 vv = *(const short8*)&Vh[(size_t)t * DH + cstage];
    #pragma unroll
    for (int j = 0; j < 8; ++j) {
      int d = cstage + j;
      sV[d * (KVB + 8) + (((t >> 3) ^ (d >> 3)) * 8) + (t & 7)] = (u16)vv[j];
    }
  }
  asm volatile("s_waitcnt vmcnt(0)" ::: "memory");
  __syncthreads();

  int sw = tile * 32 + wr * 16;
  short8 qf[2];
  qf[0] = *(const short8*)&Qh[(size_t)(sw + l15) * DH + g * 8];
  qf[1] = *(const short8*)&Qh[(size_t)(sw + l15) * DH + g * 8 + 32];

  f32x4 o[4] = {};
  float mrow[4] = {-1e30f, -1e30f, -1e30f, -1e30f};
  float lsum[4] = {};

  float* sO = (float*)&sP[0][0];   // [2][16][64] f32 overlay at flush time

  for (int it = 0; it < NIT; ++it) {
    int t0 = it * KVB;
    bool pre = (it + 1 < NIT);
    int tb = (it + 1) * KVB;

    // prefetch next V into regs (issue at top: longest latency window)
    short8 vp[4];
    if (pre) {
      #pragma unroll
      for (int q = 0; q < 4; ++q)
        vp[q] = *(const short8*)&Vh[(size_t)(tb + q * 32 + rstage) * DH + cstage];
    }

    // S1 = Q K^T (16 rows x 64 cols per wave, this wave's column half)
    f32x4 accS[4];
    #pragma unroll
    for (int ni = 0; ni < 4; ++ni) {
      int row = wc * 64 + ni * 16 + l15;
      short8 k0 = *(const short8*)&sK[row * 64 + ((g ^ (row & 7)) * 8)];
      short8 k1 = *(const short8*)&sK[row * 64 + (((4 + g) ^ (row & 7)) * 8)];
      f32x4 z = {};
      z = __builtin_amdgcn_mfma_f32_16x16x32_bf16(qf[0], k0, z, 0, 0, 0);
      z = __builtin_amdgcn_mfma_f32_16x16x32_bf16(qf[1], k1, z, 0, 0, 0);
      accS[ni] = z;
    }

    // S2 = Q E^T strip (16 x 80): rel[s,t] = q[s].E[2047 - s + t]
    int jbase = 2032 - sw + t0 + wc * 64;
    f32x4 accR[5];
    #pragma unroll
    for (int nb = 0; nb < 5; ++nb) {
      int j = jbase + nb * 16 + l15; if (j > 2047) j = 2047;
      short8 e0 = *(const short8*)&Eh[(size_t)j * DH + g * 8];
      short8 e1 = *(const short8*)&Eh[(size_t)j * DH + 32 + g * 8];
      f32x4 z = {};
      z = __builtin_amdgcn_mfma_f32_16x16x32_bf16(qf[0], e0, z, 0, 0, 0);
      z = __builtin_amdgcn_mfma_f32_16x16x32_bf16(qf[1], e1, z, 0, 0, 0);
      accR[nb] = z;
    }

    // skew realign + combine + causal mask
    bool needMask = (t0 + wc * 64 + 63 > sw);
    #pragma unroll
    for (int r = 0; r < 4; ++r) {
      int srow = g * 4 + r;
      int dsh = 15 - srow + l15;                 // 0..30
      int srcl = (lane & 48) + (dsh & 15);
      float sh[5];
      #pragma unroll
      for (int nb = 0; nb < 5; ++nb) sh[nb] = __shfl(accR[nb][r], srcl);
      bool cy = dsh >= 16;
      #pragma unroll
      for (int ni = 0; ni < 4; ++ni) {
        float rel = cy ? sh[ni + 1] : sh[ni];
        float val = accS[ni][r] + rel;
        if (needMask && (t0 + wc * 64 + ni * 16 + l15 > sw + srow)) val = -1e30f;
        accS[ni][r] = val;
      }
    }

    // local row max -> exchange across column halves
    float lmax[4];
    #pragma unroll
    for (int r = 0; r < 4; ++r) {
      float tm = fmaxf(fmaxf(accS[0][r], accS[1][r]), fmaxf(accS[2][r], accS[3][r]));
      tm = fmaxf(tm, __shfl_xor(tm, 1));
      tm = fmaxf(tm, __shfl_xor(tm, 2));
      tm = fmaxf(tm, __shfl_xor(tm, 4));
      tm = fmaxf(tm, __shfl_xor(tm, 8));
      lmax[r] = tm;
    }
    if (l15 == 0) {
      #pragma unroll
      for (int r = 0; r < 4; ++r) sM[wc][wr * 16 + g * 4 + r] = lmax[r];
    }
    __syncthreads();                              // B1: all sK reads done
    // issue next K tile into the SAME sK buffer (drained at B2)
    if (pre) {
      #pragma unroll
      for (int s = 0; s < 4; ++s) {
        int c = s * 256 + tid, t = c >> 3, pc = c & 7;
        gll16(&Kh[(size_t)(tb + t) * DH + ((pc ^ (t & 7)) * 8)],
              &sK[(size_t)(s * 256 + wv * 64) * 8]);
      }
    }
    float4 om = *(float4*)&sM[wc ^ 1][wr * 16 + g * 4];

    // global max -> rescale o, exp, local sums
    float sesav[4], lscl[4];
    #pragma unroll
    for (int r = 0; r < 4; ++r) {
      float gm = fmaxf(lmax[r], ((float*)&om)[r]);
      float mnew = fmaxf(mrow[r], gm);
      lscl[r] = exp2f(mrow[r] - mnew);
      mrow[r] = mnew;
      float se = 0.f;
      #pragma unroll
      for (int ni = 0; ni < 4; ++ni) {
        float pe = exp2f(accS[ni][r] - mnew);
        accS[ni][r] = pe;
        se += pe;
      }
      se += __shfl_xor(se, 1); se += __shfl_xor(se, 2);
      se += __shfl_xor(se, 4); se += __shfl_xor(se, 8);
      sesav[r] = se;
      o[0][r] *= lscl[r]; o[1][r] *= lscl[r]; o[2][r] *= lscl[r]; o[3][r] *= lscl[r];
    }
    if (l15 == 0) {
      #pragma unroll
      for (int r = 0; r < 4; ++r) sS[wc][wr * 16 + g * 4 + r] = sesav[r];
    }

    // P -> per-wave LDS, then PV (accumulates into rescaled o)
    #pragma unroll
    for (int ni = 0; ni < 4; ++ni)
      #pragma unroll
      for (int r = 0; r < 4; ++r) {
        int srow = g * 4 + r;
        int chunk = (ni * 2 + (l15 >> 3)) ^ (srow & 7);
        sP[wv][srow * 64 + chunk * 8 + (l15 & 7)] = f2bf(accS[ni][r]);
      }
    asm volatile("s_waitcnt lgkmcnt(0)" ::: "memory");
    __builtin_amdgcn_sched_barrier(0);
    #pragma unroll
    for (int kk = 0; kk < 2; ++kk) {
      short8 pf = *(const short8*)&sP[wv][l15 * 64 + (((kk * 4 + g) ^ (l15 & 7)) * 8)];
      #pragma unroll
      for (int nb = 0; nb < 4; ++nb) {
        int d = nb * 16 + l15;
        int ck = wc * 8 + kk * 4 + g;
        short8 vf = *(const short8*)&sV[d * (KVB + 8) + ((ck ^ (d >> 3)) * 8)];
        o[nb] = __builtin_amdgcn_mfma_f32_16x16x32_bf16(pf, vf, o[nb], 0, 0, 0);
      }
    }

    __syncthreads();                              // B2 (drains vm+lgkm: K staged)
    float4 os = *(float4*)&sS[wc ^ 1][wr * 16 + g * 4];
    #pragma unroll
    for (int r = 0; r < 4; ++r)
      lsum[r] = lsum[r] * lscl[r] + sesav[r] + ((float*)&os)[r];

    // write prefetched V^T into sV (reads of this iter are done; next
    // iteration's B1 orders these writes before its PV reads)
    if (pre) {
      #pragma unroll
      for (int q = 0; q < 4; ++q) {
        int t = q * 32 + rstage;
        #pragma unroll
        for (int j = 0; j < 8; ++j) {
          int d = cstage + j;
          sV[d * (KVB + 8) + (((t >> 3) ^ (d >> 3)) * 8) + (t & 7)] = (u16)vp[q][j];
        }
      }
    }
  }

  // ---- flush: combine column halves, normalize, store ----
  {
    if (wc == 1) {
      #pragma unroll
      for (int r = 0; r < 4; ++r) {
        float rl = 1.0f / lsum[r];
        #pragma unroll
        for (int nb = 0; nb < 4; ++nb)
          sO[wr * 1024 + (g * 4 + r) * 64 + nb * 16 + l15] = o[nb][r] * rl;
      }
    }
    __syncthreads();
    if (wc == 0) {
      #pragma unroll
      for (int r = 0; r < 4; ++r) {
        float rl = 1.0f / lsum[r];
        int ss = sw + g * 4 + r;
        #pragma unroll
        for (int nb = 0; nb < 4; ++nb) {
          float val = o[nb][r] * rl + sO[wr * 1024 + (g * 4 + r) * 64 + nb * 16 + l15];
          Ob[((size_t)(bb * SEQ + ss)) * DM + hh * DH + nb * 16 + l15] = f2bf(val);
        }
      }
    }
  }
}

// ---------------------------------------------------------------------------
extern "C" void kernel_launch(void* const* d_in, const int* in_sizes, int n_in,
                              void* d_out, int out_size, void* d_ws, size_t ws_size,
                              hipStream_t stream) {
  const float* x     = (const float*)d_in[0];
  // d_in[1] = mask: recomputed causally in-kernel
  const float* Wqkv  = (const float*)d_in[2];
  const float* bqkv  = (const float*)d_in[3];
  const float* Wproj = (const float*)d_in[4];
  const float* bproj = (const float*)d_in[5];
  const float* E     = (const float*)d_in[6];
  const float* g1    = (const float*)d_in[7];
  const float* b1    = (const float*)d_in[8];
  const float* g2    = (const float*)d_in[9];
  const float* b2    = (const float*)d_in[10];
  const float* W1    = (const float*)d_in[11];
  const float* bm1   = (const float*)d_in[12];
  const float* W2    = (const float*)d_in[13];
  const float* bm2   = (const float*)d_in[14];
  float* out = (float*)d_out;

  char* ws = (char*)d_ws;
  size_t off = 0;
  auto alloc = [&](size_t bytes) {
    void* p = ws + off;
    off += (bytes + 255) & ~(size_t)255;
    return p;
  };
  u16* a_bf   = (u16*)alloc((size_t)NROWS * DM * 2);      // LN1 out, reused for LN2 out
  u16* q_bf   = (u16*)alloc((size_t)NROWS * DM * 2);
  u16* k_bf   = (u16*)alloc((size_t)NROWS * DM * 2);
  u16* v_bf   = (u16*)alloc((size_t)NROWS * DM * 2);
  u16* att_bf = (u16*)alloc((size_t)NROWS * DM * 2);
  float* y    = (float*)alloc((size_t)NROWS * DM * 4);
  u16* h_bf   = (u16*)alloc((size_t)NROWS * 2048 * 2);
  u16* WqkvT  = (u16*)alloc((size_t)1536 * 512 * 2);
  u16* WprojT = (u16*)alloc((size_t)512 * 512 * 2);
  u16* W1T    = (u16*)alloc((size_t)2048 * 512 * 2);
  u16* W2T    = (u16*)alloc((size_t)512 * 2048 * 2);
  u16* E_bf   = (u16*)alloc((size_t)NH * SEQ * DH * 2);

  // weights -> bf16 (transposed to N x K)
  transpose_cast_kernel<<<dim3(1536 / 32, 512 / 32), 256, 0, stream>>>(Wqkv, WqkvT, 512, 1536);
  transpose_cast_kernel<<<dim3(512 / 32, 512 / 32), 256, 0, stream>>>(Wproj, WprojT, 512, 512);
  transpose_cast_kernel<<<dim3(2048 / 32, 512 / 32), 256, 0, stream>>>(W1, W1T, 512, 2048);
  transpose_cast_kernel<<<dim3(512 / 32, 2048 / 32), 256, 0, stream>>>(W2, W2T, 2048, 512);
  cast_bf16_kernel<<<(NH * SEQ * DH) / (256 * 4), 256, 0, stream>>>(E, E_bf, NH * SEQ * DH);

  // LN1
  ln_bf16_kernel<<<NROWS, 64, 0, stream>>>(x, g1, b1, a_bf);
  // QKV (q pre-scaled by 0.125*log2e); grid 768 = 64x12 (3/CU)
  gemm_bf16<64, 128, 0><<<(NROWS / 64) * (1536 / 128), 256, 0, stream>>>(
      a_bf, WqkvT, bqkv, nullptr, nullptr, q_bf, k_bf, v_bf, NROWS, 1536, 512);
  // attention (variable-length, longest-first, 1024 blocks, 3/CU)
  attn_kernel<<<1024, 256, 0, stream>>>(q_bf, k_bf, v_bf, E_bf, att_bf);
  // proj + residual -> y (fp32); grid 512 = 64x8
  gemm_bf16<64, 64, 1><<<(NROWS / 64) * (512 / 64), 256, 0, stream>>>(
      att_bf, WprojT, bproj, x, y, nullptr, nullptr, nullptr, NROWS, 512, 512);
  // LN2 (reuse a_bf as m_bf)
  ln_bf16_kernel<<<NROWS, 64, 0, stream>>>(y, g2, b2, a_bf);
  // FFN1 + gelu; grid 1024 = 64x16 (4/CU)
  gemm_bf16<64, 128, 2><<<(NROWS / 64) * (2048 / 128), 256, 0, stream>>>(
      a_bf, W1T, bm1, nullptr, nullptr, h_bf, nullptr, nullptr, NROWS, 2048, 512);
  // FFN2 + residual -> out; grid 512 = 64x8, 32 K-steps
  gemm_bf16<64, 64, 3><<<(NROWS / 64) * (512 / 64), 256, 0, stream>>>(
      h_bf, W2T, bm2, y, out, nullptr, nullptr, nullptr, NROWS, 512, 2048);
}